// Round 15
// baseline (2752.027 us; speedup 1.0000x reference)
//
#include <hip/hip_runtime.h>
#include <cstdint>

#define T_STEPS 1024
#define BATCH   32
#define DIM     1024
#define RANK    128
#define BD      (BATCH*DIM)            // 32768
#define TBD     ((size_t)T_STEPS*BD)   // 33554432
#define WSP_FLAG 262144                // flags: 1056 words (slot 0..1024 used)

typedef _Float16 half2v __attribute__((ext_vector_type(2)));

__device__ __forceinline__ float dot2f(uint32_t a, uint32_t b, float acc) {
#if __has_builtin(__builtin_amdgcn_fdot2)
  return __builtin_amdgcn_fdot2(__builtin_bit_cast(half2v, a),
                                __builtin_bit_cast(half2v, b), acc, false);
#else
  half2v xx = __builtin_bit_cast(half2v, a);
  half2v yy = __builtin_bit_cast(half2v, b);
  return acc + (float)xx[0]*(float)yy[0] + (float)xx[1]*(float)yy[1];
#endif
}

__device__ __forceinline__ float dot2x4(uint4 w, uint4 h, float acc) {
  acc = dot2f(w.x, h.x, acc); acc = dot2f(w.y, h.y, acc);
  acc = dot2f(w.z, h.z, acc); acc = dot2f(w.w, h.w, acc);
  return acc;
}

__device__ __forceinline__ uint16_t f16b(float x) {
  _Float16 h = (_Float16)x;
  return __builtin_bit_cast(unsigned short, h);
}
__device__ __forceinline__ uint32_t pack2(float a, float b) {
  return (uint32_t)f16b(a) | ((uint32_t)f16b(b) << 16);
}
__device__ __forceinline__ float fast_tanh(float x) {
  float e = __expf(2.0f*x);
  return 1.0f - 2.0f/(e + 1.0f);
}
__device__ __forceinline__ float fast_silu(float zz) {
  return zz / (1.0f + __expf(-zz));
}

__device__ __forceinline__ void pin4(uint4 &v) {
  asm volatile("" : "+v"(v.x), "+v"(v.y), "+v"(v.z), "+v"(v.w));
}

template<int CTRL>
__device__ __forceinline__ float dpp_xorf(float v) {
  int t = __builtin_amdgcn_mov_dpp(__builtin_bit_cast(int, v), CTRL, 0xf, 0xf, true);
  return __builtin_bit_cast(float, t);
}

// barrier that does NOT drain vmcnt (only LDS ordering needed between phases)
__device__ __forceinline__ void lds_barrier() {
  asm volatile("s_waitcnt lgkmcnt(0)" ::: "memory");
  __builtin_amdgcn_s_barrier();
  __builtin_amdgcn_sched_barrier(0);
}

// ---------------------------------------------------------------------------
// K0: pack weights (s folded into U), h0 -> h-slot 0, zero slot flags.
// ws layout (uint32 words):
//   [0]      vhw  [128][512]   V_h f16 pairs
//   [65536]  uqs  [26][512][4] U'_h stream layout (words 0..51, coalesced)
//   [118784] ures [1024][12]   U'_h words 52..63
//   [131072] vxw  [128][512]
//   [196608] uxw  [1024][64]
//   [262144] flags[1056]       per-slot ready flags
// ---------------------------------------------------------------------------
__global__ void prep_kernel(const float* __restrict__ Uh, const float* __restrict__ Vh,
                            const float* __restrict__ sh, const float* __restrict__ Ux,
                            const float* __restrict__ Vx, const float* __restrict__ sx,
                            const float* __restrict__ h0, uint32_t* __restrict__ ws32,
                            float* __restrict__ hout) {
  int i = blockIdx.x*blockDim.x + threadIdx.x;
  int n = gridDim.x*blockDim.x;
  for (int p = i; p < 65536; p += n) {
    int r = p >> 9, dp = p & 511;
    ws32[p] = pack2(Vh[r*1024 + 2*dp], Vh[r*1024 + 2*dp + 1]);
  }
  for (int p = i; p < 65536; p += n) {
    int d = p >> 6, k = p & 63;
    uint32_t w = pack2(Uh[d*128 + k]      * sh[k],
                       Uh[d*128 + 64 + k] * sh[64 + k]);
    if (k < 52) {
      int J = (k >> 2) + 13*(d & 1);
      ws32[65536 + J*2048 + (d >> 1)*4 + (k & 3)] = w;
    } else {
      ws32[118784 + d*12 + (k - 52)] = w;
    }
  }
  for (int p = i; p < 65536; p += n) {
    int r = p >> 9, dp = p & 511;
    ws32[131072 + p] = pack2(Vx[r*1024 + 2*dp], Vx[r*1024 + 2*dp + 1]);
  }
  for (int p = i; p < 65536; p += n) {
    int d = p >> 6, rp = p & 63;
    ws32[196608 + p] = pack2(Ux[d*128 + 2*rp]   * sx[2*rp],
                             Ux[d*128 + 2*rp+1] * sx[2*rp+1]);
  }
  for (int p = i; p < BD; p += n) hout[p] = h0[p];
  for (int p = i; p < 1056; p += n) ws32[WSP_FLAG + p] = 0;
}

// ---------------------------------------------------------------------------
// K1 (fused): WGs 0..31 = recurrence (one per batch); WGs 32..255 = input
// branch producers, each handling slots t+1 for t = (g-32) + 224k.
// inp-WGs never wait -> they always drain and free CUs -> no deadlock even
// without co-residency guarantees. rec-WGs poll per-slot flags ONE STEP
// AHEAD (cc double-buffer) so poll latency hides under compute.
// ---------------------------------------------------------------------------
__global__ __attribute__((amdgpu_flat_work_group_size(512, 512),
                          amdgpu_waves_per_eu(2, 2)))
void fused_kernel(uint32_t* __restrict__ ws32, const float* __restrict__ x,
                  const float* __restrict__ z, const float* __restrict__ bias,
                  float* __restrict__ outb) {
  __shared__ __attribute__((aligned(16))) uint8_t smem[150272];
  const int g = blockIdx.x;
  const int l = threadIdx.x;   // 0..511
  float* hout = outb + TBD;
  uint32_t* flags = ws32 + WSP_FLAG;

  if (g < 32) {
    // ===================== REC PART (v14 core) =====================
    const int b  = g;
    const int W  = l & 31;
    const int R8 = l >> 5;
    const uint4* vhw4  = (const uint4*)ws32;
    const uint4* uqs4  = (const uint4*)(ws32 + 65536);
    const uint4* ures4 = (const uint4*)(ws32 + 118784);

    uint4*    vlds  = (uint4*)smem;                     // 6144 uint4
    uint4*    ulds  = (uint4*)(smem + 98304);           // 3072 uint4
    uint32_t* hbuf  = (uint32_t*)(smem + 147456);       // 640 words
    uint32_t* svh32 = (uint32_t*)(smem + 150016);       // 64 words

    // V rows 8R8+0..4 -> VGPRs (80 words, pinned)
    uint4 vw[5][4];
    #pragma unroll
    for (int r = 0; r < 5; r++) {
      #pragma unroll
      for (int c = 0; c < 4; c++) vw[r][c] = vhw4[(8*R8 + r)*128 + W*4 + c];
    }
    #pragma unroll
    for (int r = 0; r < 5; r++) {
      #pragma unroll
      for (int c = 0; c < 4; c++) pin4(vw[r][c]);
    }
    // V rows 8R8+5..7 -> vlds
    #pragma unroll
    for (int rr = 0; rr < 3; rr++) {
      #pragma unroll
      for (int c = 0; c < 4; c++)
        vlds[R8*384 + rr*128 + c*32 + W] = vhw4[(8*R8 + 5 + rr)*128 + W*4 + c];
    }
    // U words 52..63 -> ulds
    #pragma unroll
    for (int j = 0; j < 3; j++) {
      ulds[j*512 + l]     = ures4[(2*l)*3 + j];
      ulds[(3+j)*512 + l] = ures4[(2*l+1)*3 + j];
    }
    // U words 0..51 -> arrays before the loop (allocator remats at use)
    uint4 uq0[13], uq1[13];
    #pragma unroll
    for (int J = 0; J < 13; J++) {
      uq0[J] = uqs4[J*512 + l];
      uq1[J] = uqs4[(13+J)*512 + l];
    }
    // init hbuf from h0
    {
      const float2 v = ((const float2*)(hout + (size_t)b*DIM))[l];
      hbuf[20*(l>>4) + (l&15)] = pack2(v.x, v.y);
    }
    __syncthreads();

    const float2* zp2 = (const float2*)(z + (size_t)b*DIM) + l;
    float2*       cp2 = (float2*)(hout + BD + (size_t)b*DIM) + l;
    float2*       op2 = (float2*)(outb + (size_t)b*DIM) + l;
    const uint4*  hb4  = (const uint4*)hbuf + W*5;
    const uint4*  svh4 = (const uint4*)svh32;
    const int vbase = R8*384;

    // prologue: wait for slot 1, load cc
    while (__hip_atomic_load(&flags[1], __ATOMIC_ACQUIRE,
                             __HIP_MEMORY_SCOPE_AGENT) == 0) {}
    float2 cc = *cp2;

    #pragma unroll 1
    for (int t = 0; t < T_STEPS; t++) {
      float2 zz = *zp2;
      // poll ONE STEP AHEAD: slot t+2 (latency hides under this step)
      float2 ccn = make_float2(0.f, 0.f);
      if (t < T_STEPS - 1) {
        while (__hip_atomic_load(&flags[t+2], __ATOMIC_ACQUIRE,
                                 __HIP_MEMORY_SCOPE_AGENT) == 0) {}
        ccn = cp2[BD/2];
      }

      // ---- phase A ----
      float a[8] = {0.f,0.f,0.f,0.f,0.f,0.f,0.f,0.f};
      #pragma unroll
      for (int c = 0; c < 4; c++) {
        uint4 hvc = hb4[c];
        uint4 vA = vlds[vbase + c*32 + W];
        uint4 vB = vlds[vbase + 128 + c*32 + W];
        uint4 vC = vlds[vbase + 256 + c*32 + W];
        a[0] = dot2x4(vw[0][c], hvc, a[0]);
        a[1] = dot2x4(vw[1][c], hvc, a[1]);
        a[2] = dot2x4(vw[2][c], hvc, a[2]);
        a[3] = dot2x4(vw[3][c], hvc, a[3]);
        a[4] = dot2x4(vw[4][c], hvc, a[4]);
        a[5] = dot2x4(vA, hvc, a[5]);
        a[6] = dot2x4(vB, hvc, a[6]);
        a[7] = dot2x4(vC, hvc, a[7]);
      }
      float b4[4];
      {
        const bool s0 = (W & 1);
        #pragma unroll
        for (int i = 0; i < 4; i++) {
          float keep = s0 ? a[2*i+1] : a[2*i];
          float send = s0 ? a[2*i]   : a[2*i+1];
          b4[i] = keep + dpp_xorf<0xB1>(send);
        }
      }
      float c2[2];
      {
        const bool s1 = (W >> 1) & 1;
        #pragma unroll
        for (int i = 0; i < 2; i++) {
          float keep = s1 ? b4[2*i+1] : b4[2*i];
          float send = s1 ? b4[2*i]   : b4[2*i+1];
          c2[i] = keep + dpp_xorf<0x4E>(send);
        }
      }
      float s;
      {
        const bool s2 = (W >> 2) & 1;
        float keep = s2 ? c2[1] : c2[0];
        float send = s2 ? c2[0] : c2[1];
        s = keep + __shfl_xor(send, 4);
      }
      s += __shfl_xor(s, 8);
      s += __shfl_xor(s, 16);
      if (W < 8) {
        int row = 8*R8 + W;
        int idx = ((row & 63) << 1) | (row >> 6);
        ((uint16_t*)svh32)[idx] = f16b(s);
      }
      lds_barrier();

      // ---- phase B: svh via DIRECT uniform b128 reads (no DPP) ----
      float p0 = 0.f, p1 = 0.f;
      { // quarter 0
        uint4 sv0 = svh4[0], sv1 = svh4[1], sv2 = svh4[2], sv3 = svh4[3];
        p0 = dot2x4(uq0[0], sv0, p0); p1 = dot2x4(uq1[0], sv0, p1);
        p0 = dot2x4(uq0[1], sv1, p0); p1 = dot2x4(uq1[1], sv1, p1);
        p0 = dot2x4(uq0[2], sv2, p0); p1 = dot2x4(uq1[2], sv2, p1);
        p0 = dot2x4(uq0[3], sv3, p0); p1 = dot2x4(uq1[3], sv3, p1);
      }
      { // quarter 1
        uint4 sv0 = svh4[4], sv1 = svh4[5], sv2 = svh4[6], sv3 = svh4[7];
        p0 = dot2x4(uq0[4], sv0, p0); p1 = dot2x4(uq1[4], sv0, p1);
        p0 = dot2x4(uq0[5], sv1, p0); p1 = dot2x4(uq1[5], sv1, p1);
        p0 = dot2x4(uq0[6], sv2, p0); p1 = dot2x4(uq1[6], sv2, p1);
        p0 = dot2x4(uq0[7], sv3, p0); p1 = dot2x4(uq1[7], sv3, p1);
      }
      { // quarter 2
        uint4 sv0 = svh4[8], sv1 = svh4[9], sv2 = svh4[10], sv3 = svh4[11];
        p0 = dot2x4(uq0[8],  sv0, p0); p1 = dot2x4(uq1[8],  sv0, p1);
        p0 = dot2x4(uq0[9],  sv1, p0); p1 = dot2x4(uq1[9],  sv1, p1);
        p0 = dot2x4(uq0[10], sv2, p0); p1 = dot2x4(uq1[10], sv2, p1);
        p0 = dot2x4(uq0[11], sv3, p0); p1 = dot2x4(uq1[11], sv3, p1);
      }
      { // quarter 3
        uint4 sv0 = svh4[12], sv1 = svh4[13], sv2 = svh4[14], sv3 = svh4[15];
        uint4 u0b = ulds[0*512 + l], u0c = ulds[1*512 + l], u0d = ulds[2*512 + l];
        uint4 u1b = ulds[3*512 + l], u1c = ulds[4*512 + l], u1d = ulds[5*512 + l];
        p0 = dot2x4(uq0[12], sv0, p0); p1 = dot2x4(uq1[12], sv0, p1);
        p0 = dot2x4(u0b, sv1, p0); p1 = dot2x4(u1b, sv1, p1);
        p0 = dot2x4(u0c, sv2, p0); p1 = dot2x4(u1c, sv2, p1);
        p0 = dot2x4(u0d, sv3, p0); p1 = dot2x4(u1d, sv3, p1);
      }

      float hv0 = fast_tanh(p0 + cc.x);
      float hv1 = fast_tanh(p1 + cc.y);
      *cp2 = make_float2(hv0, hv1);                             // h[t+1]
      hbuf[20*(l>>4) + (l&15)] = pack2(hv0, hv1);               // next h
      *op2 = make_float2(hv0 * fast_silu(zz.x), hv1 * fast_silu(zz.y));
      lds_barrier();

      cc = ccn;
      cp2 += BD/2; zp2 += BD/2; op2 += BD/2;
    }
  } else {
    // ===================== INP PART =====================
    uint32_t* xs  = (uint32_t*)smem;            // 32*516 words
    uint16_t* svx = (uint16_t*)(smem + 66048);  // BATCH*RANK

    const int j = g - 32;   // 0..223
    #pragma unroll 1
    for (int t = j; t < T_STEPS; t += 224) {
      const float4* xg = (const float4*)(x + (size_t)t*BD);
      #pragma unroll
      for (int k = 0; k < 16; k++) {
        int i = l + 512*k;
        float4 v = xg[i];
        int bb = i >> 8;
        int d4 = i & 255;
        xs[bb*516 + d4*2]     = pack2(v.x, v.y);
        xs[bb*516 + d4*2 + 1] = pack2(v.z, v.w);
      }
      __syncthreads();

      const int q4 = l & 3;
      const int r  = l >> 2;
      const uint4* wrow = (const uint4*)(ws32 + 131072 + r*512);
      float acc0[8], acc1[8];
      #pragma unroll
      for (int bi = 0; bi < 8; bi++) { acc0[bi] = 0.f; acc1[bi] = 0.f; }
      #pragma unroll 4
      for (int J = 0; J < 128; J += 2) {
        uint4 w0 = wrow[J];
        uint4 w1 = wrow[J+1];
        #pragma unroll
        for (int bi = 0; bi < 8; bi++) {
          const uint4* xrow = (const uint4*)(xs + (4*bi + q4)*516);
          uint4 h0v = xrow[J];
          acc0[bi] = dot2f(w0.x, h0v.x, acc0[bi]);
          acc0[bi] = dot2f(w0.y, h0v.y, acc0[bi]);
          acc0[bi] = dot2f(w0.z, h0v.z, acc0[bi]);
          acc0[bi] = dot2f(w0.w, h0v.w, acc0[bi]);
          uint4 h1v = xrow[J+1];
          acc1[bi] = dot2f(w1.x, h1v.x, acc1[bi]);
          acc1[bi] = dot2f(w1.y, h1v.y, acc1[bi]);
          acc1[bi] = dot2f(w1.z, h1v.z, acc1[bi]);
          acc1[bi] = dot2f(w1.w, h1v.w, acc1[bi]);
        }
      }
      #pragma unroll
      for (int bi = 0; bi < 8; bi++)
        svx[(4*bi + q4)*RANK + r] = f16b(acc0[bi] + acc1[bi]);
      __syncthreads();

      const uint4* svx4 = (const uint4*)svx;
      float accb[BATCH];
      #pragma unroll 1
      for (int dd = 0; dd < 2; dd++) {
        int d = l + dd*512;
        const uint4* urow = (const uint4*)(ws32 + 196608 + d*64);
        #pragma unroll
        for (int bi = 0; bi < BATCH; bi++) accb[bi] = 0.f;
        #pragma unroll
        for (int RP = 0; RP < 16; RP++) {
          uint4 w = urow[RP];
          #pragma unroll
          for (int bi = 0; bi < BATCH; bi++) {
            uint4 sv = svx4[bi*16 + RP];
            accb[bi] = dot2f(w.x, sv.x, accb[bi]);
            accb[bi] = dot2f(w.y, sv.y, accb[bi]);
            accb[bi] = dot2f(w.z, sv.z, accb[bi]);
            accb[bi] = dot2f(w.w, sv.w, accb[bi]);
          }
        }
        float bv = bias[d];
        float* cslot = hout + (size_t)(t+1)*BD + d;
        #pragma unroll
        for (int bi = 0; bi < BATCH; bi++)
          cslot[(size_t)bi*DIM] = accb[bi] + bv;
      }
      __syncthreads();   // drains vmcnt: all c stores in L2
      if (l == 0)
        __hip_atomic_store(&flags[t+1], 1u, __ATOMIC_RELEASE,
                           __HIP_MEMORY_SCOPE_AGENT);
      __syncthreads();   // xs reuse safety for next slot
    }
  }
}

extern "C" void kernel_launch(void* const* d_in, const int* in_sizes, int n_in,
                              void* d_out, int out_size, void* d_ws, size_t ws_size,
                              hipStream_t stream) {
  const float* x  = (const float*)d_in[0];
  const float* z  = (const float*)d_in[1];
  const float* h0 = (const float*)d_in[2];
  const float* Uh = (const float*)d_in[3];
  const float* Vh = (const float*)d_in[4];
  const float* sh = (const float*)d_in[5];
  const float* Ux = (const float*)d_in[6];
  const float* Vx = (const float*)d_in[7];
  const float* sx = (const float*)d_in[8];
  const float* bb = (const float*)d_in[9];
  float* outb = (float*)d_out;
  uint32_t* ws32 = (uint32_t*)d_ws;   // needs ~1.01 MiB

  prep_kernel<<<512, 256, 0, stream>>>(Uh, Vh, sh, Ux, Vx, sx, h0, ws32, outb + TBD);
  fused_kernel<<<256, 512, 0, stream>>>(ws32, x, z, bb, outb);
}

// Round 16
// 2226.290 us; speedup vs baseline: 1.2361x; 1.2361x over previous
//
#include <hip/hip_runtime.h>
#include <cstdint>

#define T_STEPS 1024
#define BATCH   32
#define DIM     1024
#define RANK    128
#define BD      (BATCH*DIM)            // 32768
#define TBD     ((size_t)T_STEPS*BD)   // 33554432

typedef _Float16 half2v __attribute__((ext_vector_type(2)));

__device__ __forceinline__ float dot2f(uint32_t a, uint32_t b, float acc) {
#if __has_builtin(__builtin_amdgcn_fdot2)
  return __builtin_amdgcn_fdot2(__builtin_bit_cast(half2v, a),
                                __builtin_bit_cast(half2v, b), acc, false);
#else
  half2v xx = __builtin_bit_cast(half2v, a);
  half2v yy = __builtin_bit_cast(half2v, b);
  return acc + (float)xx[0]*(float)yy[0] + (float)xx[1]*(float)yy[1];
#endif
}

__device__ __forceinline__ float dot2x4(uint4 w, uint4 h, float acc) {
  acc = dot2f(w.x, h.x, acc); acc = dot2f(w.y, h.y, acc);
  acc = dot2f(w.z, h.z, acc); acc = dot2f(w.w, h.w, acc);
  return acc;
}

__device__ __forceinline__ uint16_t f16b(float x) {
  _Float16 h = (_Float16)x;
  return __builtin_bit_cast(unsigned short, h);
}
__device__ __forceinline__ uint32_t pack2(float a, float b) {
  return (uint32_t)f16b(a) | ((uint32_t)f16b(b) << 16);
}
__device__ __forceinline__ float fast_tanh(float x) {
  float e = __expf(2.0f*x);
  return 1.0f - 2.0f/(e + 1.0f);
}
__device__ __forceinline__ float fast_silu(float zz) {
  return zz / (1.0f + __expf(-zz));
}

__device__ __forceinline__ void pin4(uint4 &v) {
  asm volatile("" : "+v"(v.x), "+v"(v.y), "+v"(v.z), "+v"(v.w));
}

template<int CTRL>
__device__ __forceinline__ float dpp_xorf(float v) {
  int t = __builtin_amdgcn_mov_dpp(__builtin_bit_cast(int, v), CTRL, 0xf, 0xf, true);
  return __builtin_bit_cast(float, t);
}

// barrier that does NOT drain vmcnt (only LDS ordering needed between phases)
__device__ __forceinline__ void lds_barrier() {
  asm volatile("s_waitcnt lgkmcnt(0)" ::: "memory");
  __builtin_amdgcn_s_barrier();
  __builtin_amdgcn_sched_barrier(0);
}

// ---------------------------------------------------------------------------
// K0: pack weights (s folded into U), h0 -> h-slot 0.
// ws layout (uint32 words):
//   [0]      vhw  [128][512]   V_h f16 pairs
//   [65536]  uqs  [26][512][4] U'_h stream layout (words 0..51, coalesced)
//   [118784] ures [1024][12]   U'_h words 52..63
//   [131072] vxw  [128][512]   V_x (row-major pairs)
//   [196608] uxc  [2][16][512][4] U'_x COALESCED chunks: uint4 J of row d at
//                              196608 + (d>>9)*32768 + J*2048 + (d&511)*4
// ---------------------------------------------------------------------------
__global__ void prep_kernel(const float* __restrict__ Uh, const float* __restrict__ Vh,
                            const float* __restrict__ sh, const float* __restrict__ Ux,
                            const float* __restrict__ Vx, const float* __restrict__ sx,
                            const float* __restrict__ h0, uint32_t* __restrict__ ws32,
                            float* __restrict__ hout) {
  int i = blockIdx.x*blockDim.x + threadIdx.x;
  int n = gridDim.x*blockDim.x;
  for (int p = i; p < 65536; p += n) {
    int r = p >> 9, dp = p & 511;
    ws32[p] = pack2(Vh[r*1024 + 2*dp], Vh[r*1024 + 2*dp + 1]);
  }
  for (int p = i; p < 65536; p += n) {
    int d = p >> 6, k = p & 63;
    uint32_t w = pack2(Uh[d*128 + k]      * sh[k],
                       Uh[d*128 + 64 + k] * sh[64 + k]);
    if (k < 52) {
      int J = (k >> 2) + 13*(d & 1);
      ws32[65536 + J*2048 + (d >> 1)*4 + (k & 3)] = w;
    } else {
      ws32[118784 + d*12 + (k - 52)] = w;
    }
  }
  for (int p = i; p < 65536; p += n) {
    int r = p >> 9, dp = p & 511;
    ws32[131072 + p] = pack2(Vx[r*1024 + 2*dp], Vx[r*1024 + 2*dp + 1]);
  }
  for (int p = i; p < 65536; p += n) {
    int d = p >> 6, k = p & 63;
    uint32_t w = pack2(Ux[d*128 + 2*k]   * sx[2*k],
                       Ux[d*128 + 2*k+1] * sx[2*k+1]);
    ws32[196608 + (d >> 9)*32768 + (k >> 2)*2048 + (d & 511)*4 + (k & 3)] = w;
  }
  for (int p = i; p < BD; p += n) hout[p] = h0[p];
}

// ---------------------------------------------------------------------------
// K1: input branch v2. One WG (512 thr) per timestep t.
// GEMM1 re-tiled: thread = (rq=l>>4 -> rows 4rq..4rq+3, bq=l&15 -> b rows
// {bq, bq+16}). DS reads 1024 -> 256 per thread (was DS-pipe-bound); w-reads
// are 16-lane-uniform, streaming-sequential per row (L1 temporal reuse).
// GEMM2: U_x from the coalesced uxc chunk layout (lane-stride 16B).
// ---------------------------------------------------------------------------
__global__ __launch_bounds__(512, 4) void inp_kernel(
    const float* __restrict__ x, const uint32_t* __restrict__ ws32,
    const float* __restrict__ bias, float* __restrict__ hout) {
  const int t = blockIdx.x;
  const int l = threadIdx.x;  // 0..511
  __shared__ __attribute__((aligned(16))) uint32_t xs[32*516];   // 66 KB
  __shared__ __attribute__((aligned(16))) uint32_t svx[32*64];   // 8 KB

  // stage x_t -> LDS f16 pairs (staggered rows, stride 516)
  const float4* xg = (const float4*)(x + (size_t)t*BD);
  #pragma unroll
  for (int k = 0; k < 16; k++) {
    int i = l + 512*k;
    float4 v = xg[i];
    int bb = i >> 8;
    int d4 = i & 255;
    xs[bb*516 + d4*2]     = pack2(v.x, v.y);
    xs[bb*516 + d4*2 + 1] = pack2(v.z, v.w);
  }
  __syncthreads();

  // ---- GEMM1: sv[b][r] = sum_d Vx[r][d] x[b][d], thread = 4r x 2b ----
  const int rq = l >> 4;      // rows 4rq..4rq+3
  const int bq = l & 15;      // b rows bq, bq+16
  const uint4* xr0 = (const uint4*)(xs + bq*516);
  const uint4* xr1 = (const uint4*)(xs + (bq+16)*516);
  const uint4* wr0 = (const uint4*)(ws32 + 131072 + (4*rq    )*512);
  const uint4* wr1 = (const uint4*)(ws32 + 131072 + (4*rq + 1)*512);
  const uint4* wr2 = (const uint4*)(ws32 + 131072 + (4*rq + 2)*512);
  const uint4* wr3 = (const uint4*)(ws32 + 131072 + (4*rq + 3)*512);
  float a00=0.f,a01=0.f,a10=0.f,a11=0.f,a20=0.f,a21=0.f,a30=0.f,a31=0.f;
  #pragma unroll 2
  for (int J = 0; J < 128; J++) {
    uint4 x0 = xr0[J];
    uint4 x1 = xr1[J];
    uint4 w0 = wr0[J];
    uint4 w1 = wr1[J];
    uint4 w2 = wr2[J];
    uint4 w3 = wr3[J];
    a00 = dot2x4(w0, x0, a00); a01 = dot2x4(w0, x1, a01);
    a10 = dot2x4(w1, x0, a10); a11 = dot2x4(w1, x1, a11);
    a20 = dot2x4(w2, x0, a20); a21 = dot2x4(w2, x1, a21);
    a30 = dot2x4(w3, x0, a30); a31 = dot2x4(w3, x1, a31);
  }
  // svx row b: word k = f16 pair (r=2k, 2k+1); thread writes words 2rq,2rq+1
  ((uint2*)(svx + bq*64))[rq]      = make_uint2(pack2(a00, a10), pack2(a20, a30));
  ((uint2*)(svx + (bq+16)*64))[rq] = make_uint2(pack2(a01, a11), pack2(a21, a31));
  __syncthreads();

  // ---- GEMM2: c[b][d] = sum_r Ux'[d][r] sv[b][r] + bias[d] ----
  const uint4* svx4 = (const uint4*)svx;   // [b][16] uint4
  float accb[BATCH];
  #pragma unroll 1
  for (int dd = 0; dd < 2; dd++) {
    int d = l + dd*512;
    const uint4* uc = (const uint4*)(ws32 + 196608 + dd*32768);  // + RP*512 + l
    #pragma unroll
    for (int bi = 0; bi < BATCH; bi++) accb[bi] = 0.f;
    #pragma unroll
    for (int RP = 0; RP < 16; RP++) {
      uint4 w = uc[RP*512 + l];
      #pragma unroll
      for (int bi = 0; bi < BATCH; bi++) {
        uint4 sv = svx4[bi*16 + RP];
        accb[bi] = dot2f(w.x, sv.x, accb[bi]);
        accb[bi] = dot2f(w.y, sv.y, accb[bi]);
        accb[bi] = dot2f(w.z, sv.z, accb[bi]);
        accb[bi] = dot2f(w.w, sv.w, accb[bi]);
      }
    }
    float bv = bias[d];
    float* cslot = hout + (size_t)(t+1)*BD + d;
    #pragma unroll
    for (int bi = 0; bi < BATCH; bi++)
      cslot[(size_t)bi*DIM] = accb[bi] + bv;
  }
}

// ---------------------------------------------------------------------------
// K2: recurrence (R14 verbatim — 1952us best). One WG (512 thr, 2 waves/SIMD)
// per batch. regs 80 w V (pinned); LDS 147 KB (V rows 5..7 + U words 52..63);
// stream 208 KB/step U words 0..51 (coalesced layout, remat'd by allocator).
// ---------------------------------------------------------------------------
__global__ __attribute__((amdgpu_flat_work_group_size(512, 512),
                          amdgpu_waves_per_eu(2, 2)))
void rec_kernel(
    const uint32_t* __restrict__ ws32, const float* __restrict__ z,
    float* __restrict__ outb) {
  const int b  = blockIdx.x;
  const int l  = threadIdx.x;  // 0..511
  const int W  = l & 31;
  const int R8 = l >> 5;       // 0..15
  const int m  = l & 3;
  float* hout = outb + TBD;
  const uint4* vhw4  = (const uint4*)ws32;
  const uint4* uqs4  = (const uint4*)(ws32 + 65536);
  const uint4* ures4 = (const uint4*)(ws32 + 118784);

  __shared__ __attribute__((aligned(16))) uint4    vlds[6144];   // 96 KB
  __shared__ __attribute__((aligned(16))) uint4    ulds[3072];   // 48 KB
  __shared__ __attribute__((aligned(16))) uint4    hbuf[32*5];   // 2.5 KB staggered
  __shared__ __attribute__((aligned(16))) uint32_t svh32[64];    // 256 B

  uint4 vw[5][4];
  #pragma unroll
  for (int r = 0; r < 5; r++) {
    #pragma unroll
    for (int c = 0; c < 4; c++) vw[r][c] = vhw4[(8*R8 + r)*128 + W*4 + c];
  }
  #pragma unroll
  for (int r = 0; r < 5; r++) {
    #pragma unroll
    for (int c = 0; c < 4; c++) pin4(vw[r][c]);
  }
  #pragma unroll
  for (int rr = 0; rr < 3; rr++) {
    #pragma unroll
    for (int c = 0; c < 4; c++)
      vlds[R8*384 + rr*128 + c*32 + W] = vhw4[(8*R8 + 5 + rr)*128 + W*4 + c];
  }
  #pragma unroll
  for (int j = 0; j < 3; j++) {
    ulds[j*512 + l]     = ures4[(2*l)*3 + j];
    ulds[(3+j)*512 + l] = ures4[(2*l+1)*3 + j];
  }
  uint4 uq0[13], uq1[13];
  #pragma unroll
  for (int J = 0; J < 13; J++) {
    uq0[J] = uqs4[J*512 + l];
    uq1[J] = uqs4[(13+J)*512 + l];
  }
  {
    const float2 v = ((const float2*)(hout + (size_t)b*DIM))[l];
    ((uint32_t*)hbuf)[20*(l>>4) + (l&15)] = pack2(v.x, v.y);
  }
  __syncthreads();

  const float2* zp2 = (const float2*)(z + (size_t)b*DIM) + l;
  float2*       cp2 = (float2*)(hout + BD + (size_t)b*DIM) + l;
  float2*       op2 = (float2*)(outb + (size_t)b*DIM) + l;
  const uint4*  hb4  = hbuf + W*5;
  const uint4*  svh4 = (const uint4*)svh32;
  const int vbase = R8*384;

  #pragma unroll 1
  for (int t = 0; t < T_STEPS; t++) {
    float2 cc = *cp2;
    float2 zz = *zp2;

    float a[8] = {0.f,0.f,0.f,0.f,0.f,0.f,0.f,0.f};
    #pragma unroll
    for (int c = 0; c < 4; c++) {
      uint4 hvc = hb4[c];
      uint4 vA = vlds[vbase + c*32 + W];
      uint4 vB = vlds[vbase + 128 + c*32 + W];
      uint4 vC = vlds[vbase + 256 + c*32 + W];
      a[0] = dot2x4(vw[0][c], hvc, a[0]);
      a[1] = dot2x4(vw[1][c], hvc, a[1]);
      a[2] = dot2x4(vw[2][c], hvc, a[2]);
      a[3] = dot2x4(vw[3][c], hvc, a[3]);
      a[4] = dot2x4(vw[4][c], hvc, a[4]);
      a[5] = dot2x4(vA, hvc, a[5]);
      a[6] = dot2x4(vB, hvc, a[6]);
      a[7] = dot2x4(vC, hvc, a[7]);
    }
    float b4[4];
    {
      const bool s0 = (W & 1);
      #pragma unroll
      for (int i = 0; i < 4; i++) {
        float keep = s0 ? a[2*i+1] : a[2*i];
        float send = s0 ? a[2*i]   : a[2*i+1];
        b4[i] = keep + dpp_xorf<0xB1>(send);
      }
    }
    float c2[2];
    {
      const bool s1 = (W >> 1) & 1;
      #pragma unroll
      for (int i = 0; i < 2; i++) {
        float keep = s1 ? b4[2*i+1] : b4[2*i];
        float send = s1 ? b4[2*i]   : b4[2*i+1];
        c2[i] = keep + dpp_xorf<0x4E>(send);
      }
    }
    float s;
    {
      const bool s2 = (W >> 2) & 1;
      float keep = s2 ? c2[1] : c2[0];
      float send = s2 ? c2[0] : c2[1];
      s = keep + __shfl_xor(send, 4);
    }
    s += __shfl_xor(s, 8);
    s += __shfl_xor(s, 16);
    if (W < 8) {
      int row = 8*R8 + W;
      int idx = ((row & 63) << 1) | (row >> 6);
      ((uint16_t*)svh32)[idx] = f16b(s);
    }
    lds_barrier();

    float p0 = 0.f, p1 = 0.f;
    {
      uint4 svm = svh4[m];
      uint4 sv;
      sv.x = __builtin_amdgcn_mov_dpp((int)svm.x, 0*0x55, 0xf, 0xf, true);
      // quarter 0 via per-component DPP broadcast of lane m? -- keep R14 form:
    }
    { // quarter 0: uint4 0..3
      uint4 sv0 = svh4[0], sv1 = svh4[1], sv2 = svh4[2], sv3 = svh4[3];
      p0 = dot2x4(uq0[0], sv0, p0); p1 = dot2x4(uq1[0], sv0, p1);
      p0 = dot2x4(uq0[1], sv1, p0); p1 = dot2x4(uq1[1], sv1, p1);
      p0 = dot2x4(uq0[2], sv2, p0); p1 = dot2x4(uq1[2], sv2, p1);
      p0 = dot2x4(uq0[3], sv3, p0); p1 = dot2x4(uq1[3], sv3, p1);
    }
    { // quarter 1: uint4 4..7
      uint4 sv0 = svh4[4], sv1 = svh4[5], sv2 = svh4[6], sv3 = svh4[7];
      p0 = dot2x4(uq0[4], sv0, p0); p1 = dot2x4(uq1[4], sv0, p1);
      p0 = dot2x4(uq0[5], sv1, p0); p1 = dot2x4(uq1[5], sv1, p1);
      p0 = dot2x4(uq0[6], sv2, p0); p1 = dot2x4(uq1[6], sv2, p1);
      p0 = dot2x4(uq0[7], sv3, p0); p1 = dot2x4(uq1[7], sv3, p1);
    }
    { // quarter 2: uint4 8..11
      uint4 sv0 = svh4[8], sv1 = svh4[9], sv2 = svh4[10], sv3 = svh4[11];
      p0 = dot2x4(uq0[8],  sv0, p0); p1 = dot2x4(uq1[8],  sv0, p1);
      p0 = dot2x4(uq0[9],  sv1, p0); p1 = dot2x4(uq1[9],  sv1, p1);
      p0 = dot2x4(uq0[10], sv2, p0); p1 = dot2x4(uq1[10], sv2, p1);
      p0 = dot2x4(uq0[11], sv3, p0); p1 = dot2x4(uq1[11], sv3, p1);
    }
    { // quarter 3: uint4 12 streamed + words 52..63 from ulds
      uint4 sv0 = svh4[12], sv1 = svh4[13], sv2 = svh4[14], sv3 = svh4[15];
      uint4 u0b = ulds[0*512 + l], u0c = ulds[1*512 + l], u0d = ulds[2*512 + l];
      uint4 u1b = ulds[3*512 + l], u1c = ulds[4*512 + l], u1d = ulds[5*512 + l];
      p0 = dot2x4(uq0[12], sv0, p0); p1 = dot2x4(uq1[12], sv0, p1);
      p0 = dot2x4(u0b, sv1, p0); p1 = dot2x4(u1b, sv1, p1);
      p0 = dot2x4(u0c, sv2, p0); p1 = dot2x4(u1c, sv2, p1);
      p0 = dot2x4(u0d, sv3, p0); p1 = dot2x4(u1d, sv3, p1);
    }

    float hv0 = fast_tanh(p0 + cc.x);
    float hv1 = fast_tanh(p1 + cc.y);
    *cp2 = make_float2(hv0, hv1);
    ((uint32_t*)hbuf)[20*(l>>4) + (l&15)] = pack2(hv0, hv1);
    *op2 = make_float2(hv0 * fast_silu(zz.x), hv1 * fast_silu(zz.y));
    lds_barrier();

    cp2 += BD/2; zp2 += BD/2; op2 += BD/2;
  }
}

extern "C" void kernel_launch(void* const* d_in, const int* in_sizes, int n_in,
                              void* d_out, int out_size, void* d_ws, size_t ws_size,
                              hipStream_t stream) {
  const float* x  = (const float*)d_in[0];
  const float* z  = (const float*)d_in[1];
  const float* h0 = (const float*)d_in[2];
  const float* Uh = (const float*)d_in[3];
  const float* Vh = (const float*)d_in[4];
  const float* sh = (const float*)d_in[5];
  const float* Ux = (const float*)d_in[6];
  const float* Vx = (const float*)d_in[7];
  const float* sx = (const float*)d_in[8];
  const float* bb = (const float*)d_in[9];
  float* outb = (float*)d_out;
  uint32_t* ws32 = (uint32_t*)d_ws;   // needs 1 MiB

  prep_kernel<<<512, 256, 0, stream>>>(Uh, Vh, sh, Ux, Vx, sx, h0, ws32, outb + TBD);
  inp_kernel<<<T_STEPS, 512, 0, stream>>>(x, ws32, bb, outb + TBD);
  rec_kernel<<<BATCH, 512, 0, stream>>>(ws32, z, outb);
}

// Round 17
// 2171.502 us; speedup vs baseline: 1.2673x; 1.0252x over previous
//
#include <hip/hip_runtime.h>
#include <cstdint>

#define T_STEPS 1024
#define BATCH   32
#define DIM     1024
#define RANK    128
#define BD      (BATCH*DIM)            // 32768
#define TBD     ((size_t)T_STEPS*BD)   // 33554432

typedef _Float16 half2v __attribute__((ext_vector_type(2)));

__device__ __forceinline__ float dot2f(uint32_t a, uint32_t b, float acc) {
#if __has_builtin(__builtin_amdgcn_fdot2)
  return __builtin_amdgcn_fdot2(__builtin_bit_cast(half2v, a),
                                __builtin_bit_cast(half2v, b), acc, false);
#else
  half2v xx = __builtin_bit_cast(half2v, a);
  half2v yy = __builtin_bit_cast(half2v, b);
  return acc + (float)xx[0]*(float)yy[0] + (float)xx[1]*(float)yy[1];
#endif
}

__device__ __forceinline__ float dot2x4(uint4 w, uint4 h, float acc) {
  acc = dot2f(w.x, h.x, acc); acc = dot2f(w.y, h.y, acc);
  acc = dot2f(w.z, h.z, acc); acc = dot2f(w.w, h.w, acc);
  return acc;
}

__device__ __forceinline__ uint16_t f16b(float x) {
  _Float16 h = (_Float16)x;
  return __builtin_bit_cast(unsigned short, h);
}
__device__ __forceinline__ uint32_t pack2(float a, float b) {
  return (uint32_t)f16b(a) | ((uint32_t)f16b(b) << 16);
}
__device__ __forceinline__ float fast_tanh(float x) {
  float e = __expf(2.0f*x);
  return 1.0f - 2.0f/(e + 1.0f);
}
__device__ __forceinline__ float fast_silu(float zz) {
  return zz / (1.0f + __expf(-zz));
}

__device__ __forceinline__ void pin4(uint4 &v) {
  asm volatile("" : "+v"(v.x), "+v"(v.y), "+v"(v.z), "+v"(v.w));
}

template<int CTRL>
__device__ __forceinline__ float dpp_xorf(float v) {
  int t = __builtin_amdgcn_mov_dpp(__builtin_bit_cast(int, v), CTRL, 0xf, 0xf, true);
  return __builtin_bit_cast(float, t);
}

// barrier that does NOT drain vmcnt (only LDS ordering needed between phases)
__device__ __forceinline__ void lds_barrier() {
  asm volatile("s_waitcnt lgkmcnt(0)" ::: "memory");
  __builtin_amdgcn_s_barrier();
  __builtin_amdgcn_sched_barrier(0);
}

// ---------------------------------------------------------------------------
// K0: pack weights (s folded into U), h0 -> h-slot 0.
// ws layout (uint32 words):
//   [0]      vhw  [128][512]   V_h f16 pairs
//   [65536]  uqs  [26][512][4] U'_h stream layout (words 0..51, coalesced)
//   [118784] ures [1024][12]   U'_h words 52..63
//   [131072] vxw  [128][512]   V_x (row-major pairs)
//   [196608] uxc  [2][16][512][4] U'_x COALESCED chunks: uint4 J of row d at
//                              196608 + (d>>9)*32768 + J*2048 + (d&511)*4
// ---------------------------------------------------------------------------
__global__ void prep_kernel(const float* __restrict__ Uh, const float* __restrict__ Vh,
                            const float* __restrict__ sh, const float* __restrict__ Ux,
                            const float* __restrict__ Vx, const float* __restrict__ sx,
                            const float* __restrict__ h0, uint32_t* __restrict__ ws32,
                            float* __restrict__ hout) {
  int i = blockIdx.x*blockDim.x + threadIdx.x;
  int n = gridDim.x*blockDim.x;
  for (int p = i; p < 65536; p += n) {
    int r = p >> 9, dp = p & 511;
    ws32[p] = pack2(Vh[r*1024 + 2*dp], Vh[r*1024 + 2*dp + 1]);
  }
  for (int p = i; p < 65536; p += n) {
    int d = p >> 6, k = p & 63;
    uint32_t w = pack2(Uh[d*128 + k]      * sh[k],
                       Uh[d*128 + 64 + k] * sh[64 + k]);
    if (k < 52) {
      int J = (k >> 2) + 13*(d & 1);
      ws32[65536 + J*2048 + (d >> 1)*4 + (k & 3)] = w;
    } else {
      ws32[118784 + d*12 + (k - 52)] = w;
    }
  }
  for (int p = i; p < 65536; p += n) {
    int r = p >> 9, dp = p & 511;
    ws32[131072 + p] = pack2(Vx[r*1024 + 2*dp], Vx[r*1024 + 2*dp + 1]);
  }
  for (int p = i; p < 65536; p += n) {
    int d = p >> 6, k = p & 63;
    uint32_t w = pack2(Ux[d*128 + 2*k]   * sx[2*k],
                       Ux[d*128 + 2*k+1] * sx[2*k+1]);
    ws32[196608 + (d >> 9)*32768 + (k >> 2)*2048 + (d & 511)*4 + (k & 3)] = w;
  }
  for (int p = i; p < BD; p += n) hout[p] = h0[p];
}

// ---------------------------------------------------------------------------
// K1: input branch v3. One WG (512 thr) per timestep t.
// CHANGE vs v2: register cap lifted. __launch_bounds__(512,4) capped inp at
// 64 VGPR/lane since R1 -> GEMM2's accb[32] (+16 live sv words) spilled to
// scratch every RP iteration = the hidden ~5x cost. waves_per_eu(2,4):
// min 2 -> 256-reg budget (no spill), max 4 -> 2 WGs/CU still allowed.
// ---------------------------------------------------------------------------
__global__ __attribute__((amdgpu_flat_work_group_size(512, 512),
                          amdgpu_waves_per_eu(2, 4)))
void inp_kernel(
    const float* __restrict__ x, const uint32_t* __restrict__ ws32,
    const float* __restrict__ bias, float* __restrict__ hout) {
  const int t = blockIdx.x;
  const int l = threadIdx.x;  // 0..511
  __shared__ __attribute__((aligned(16))) uint32_t xs[32*516];   // 66 KB
  __shared__ __attribute__((aligned(16))) uint32_t svx[32*64];   // 8 KB

  // stage x_t -> LDS f16 pairs (staggered rows, stride 516)
  const float4* xg = (const float4*)(x + (size_t)t*BD);
  #pragma unroll
  for (int k = 0; k < 16; k++) {
    int i = l + 512*k;
    float4 v = xg[i];
    int bb = i >> 8;
    int d4 = i & 255;
    xs[bb*516 + d4*2]     = pack2(v.x, v.y);
    xs[bb*516 + d4*2 + 1] = pack2(v.z, v.w);
  }
  __syncthreads();

  // ---- GEMM1: sv[b][r] = sum_d Vx[r][d] x[b][d], thread = 4r x 2b ----
  const int rq = l >> 4;      // rows 4rq..4rq+3
  const int bq = l & 15;      // b rows bq, bq+16
  const uint4* xr0 = (const uint4*)(xs + bq*516);
  const uint4* xr1 = (const uint4*)(xs + (bq+16)*516);
  const uint4* wr0 = (const uint4*)(ws32 + 131072 + (4*rq    )*512);
  const uint4* wr1 = (const uint4*)(ws32 + 131072 + (4*rq + 1)*512);
  const uint4* wr2 = (const uint4*)(ws32 + 131072 + (4*rq + 2)*512);
  const uint4* wr3 = (const uint4*)(ws32 + 131072 + (4*rq + 3)*512);
  float a00=0.f,a01=0.f,a10=0.f,a11=0.f,a20=0.f,a21=0.f,a30=0.f,a31=0.f;
  #pragma unroll 2
  for (int J = 0; J < 128; J++) {
    uint4 x0 = xr0[J];
    uint4 x1 = xr1[J];
    uint4 w0 = wr0[J];
    uint4 w1 = wr1[J];
    uint4 w2 = wr2[J];
    uint4 w3 = wr3[J];
    a00 = dot2x4(w0, x0, a00); a01 = dot2x4(w0, x1, a01);
    a10 = dot2x4(w1, x0, a10); a11 = dot2x4(w1, x1, a11);
    a20 = dot2x4(w2, x0, a20); a21 = dot2x4(w2, x1, a21);
    a30 = dot2x4(w3, x0, a30); a31 = dot2x4(w3, x1, a31);
  }
  // svx row b: word k = f16 pair (r=2k, 2k+1); thread writes words 2rq,2rq+1
  ((uint2*)(svx + bq*64))[rq]      = make_uint2(pack2(a00, a10), pack2(a20, a30));
  ((uint2*)(svx + (bq+16)*64))[rq] = make_uint2(pack2(a01, a11), pack2(a21, a31));
  __syncthreads();

  // ---- GEMM2: c[b][d] = sum_r Ux'[d][r] sv[b][r] + bias[d] ----
  const uint4* svx4 = (const uint4*)svx;   // [b][16] uint4
  float accb[BATCH];
  #pragma unroll 1
  for (int dd = 0; dd < 2; dd++) {
    int d = l + dd*512;
    const uint4* uc = (const uint4*)(ws32 + 196608 + dd*32768);  // + RP*512 + l
    #pragma unroll
    for (int bi = 0; bi < BATCH; bi++) accb[bi] = 0.f;
    #pragma unroll
    for (int RP = 0; RP < 16; RP++) {
      uint4 w = uc[RP*512 + l];
      #pragma unroll
      for (int bi = 0; bi < BATCH; bi++) {
        uint4 sv = svx4[bi*16 + RP];
        accb[bi] = dot2f(w.x, sv.x, accb[bi]);
        accb[bi] = dot2f(w.y, sv.y, accb[bi]);
        accb[bi] = dot2f(w.z, sv.z, accb[bi]);
        accb[bi] = dot2f(w.w, sv.w, accb[bi]);
      }
    }
    float bv = bias[d];
    float* cslot = hout + (size_t)(t+1)*BD + d;
    #pragma unroll
    for (int bi = 0; bi < BATCH; bi++)
      cslot[(size_t)bi*DIM] = accb[bi] + bv;
  }
}

// ---------------------------------------------------------------------------
// K2: recurrence (R16 verbatim, best: 1766us). One WG (512 thr, 2 waves/SIMD)
// per batch. regs 80 w V (pinned); LDS 147 KB (V rows 5..7 + U words 52..63);
// stream 208 KB/step U words 0..51 (coalesced, remat'd); svh direct b128.
// ---------------------------------------------------------------------------
__global__ __attribute__((amdgpu_flat_work_group_size(512, 512),
                          amdgpu_waves_per_eu(2, 2)))
void rec_kernel(
    const uint32_t* __restrict__ ws32, const float* __restrict__ z,
    float* __restrict__ outb) {
  const int b  = blockIdx.x;
  const int l  = threadIdx.x;  // 0..511
  const int W  = l & 31;
  const int R8 = l >> 5;       // 0..15
  float* hout = outb + TBD;
  const uint4* vhw4  = (const uint4*)ws32;
  const uint4* uqs4  = (const uint4*)(ws32 + 65536);
  const uint4* ures4 = (const uint4*)(ws32 + 118784);

  __shared__ __attribute__((aligned(16))) uint4    vlds[6144];   // 96 KB
  __shared__ __attribute__((aligned(16))) uint4    ulds[3072];   // 48 KB
  __shared__ __attribute__((aligned(16))) uint4    hbuf[32*5];   // 2.5 KB staggered
  __shared__ __attribute__((aligned(16))) uint32_t svh32[64];    // 256 B

  uint4 vw[5][4];
  #pragma unroll
  for (int r = 0; r < 5; r++) {
    #pragma unroll
    for (int c = 0; c < 4; c++) vw[r][c] = vhw4[(8*R8 + r)*128 + W*4 + c];
  }
  #pragma unroll
  for (int r = 0; r < 5; r++) {
    #pragma unroll
    for (int c = 0; c < 4; c++) pin4(vw[r][c]);
  }
  #pragma unroll
  for (int rr = 0; rr < 3; rr++) {
    #pragma unroll
    for (int c = 0; c < 4; c++)
      vlds[R8*384 + rr*128 + c*32 + W] = vhw4[(8*R8 + 5 + rr)*128 + W*4 + c];
  }
  #pragma unroll
  for (int j = 0; j < 3; j++) {
    ulds[j*512 + l]     = ures4[(2*l)*3 + j];
    ulds[(3+j)*512 + l] = ures4[(2*l+1)*3 + j];
  }
  uint4 uq0[13], uq1[13];
  #pragma unroll
  for (int J = 0; J < 13; J++) {
    uq0[J] = uqs4[J*512 + l];
    uq1[J] = uqs4[(13+J)*512 + l];
  }
  {
    const float2 v = ((const float2*)(hout + (size_t)b*DIM))[l];
    ((uint32_t*)hbuf)[20*(l>>4) + (l&15)] = pack2(v.x, v.y);
  }
  __syncthreads();

  const float2* zp2 = (const float2*)(z + (size_t)b*DIM) + l;
  float2*       cp2 = (float2*)(hout + BD + (size_t)b*DIM) + l;
  float2*       op2 = (float2*)(outb + (size_t)b*DIM) + l;
  const uint4*  hb4  = hbuf + W*5;
  const uint4*  svh4 = (const uint4*)svh32;
  const int vbase = R8*384;

  #pragma unroll 1
  for (int t = 0; t < T_STEPS; t++) {
    float2 cc = *cp2;
    float2 zz = *zp2;

    float a[8] = {0.f,0.f,0.f,0.f,0.f,0.f,0.f,0.f};
    #pragma unroll
    for (int c = 0; c < 4; c++) {
      uint4 hvc = hb4[c];
      uint4 vA = vlds[vbase + c*32 + W];
      uint4 vB = vlds[vbase + 128 + c*32 + W];
      uint4 vC = vlds[vbase + 256 + c*32 + W];
      a[0] = dot2x4(vw[0][c], hvc, a[0]);
      a[1] = dot2x4(vw[1][c], hvc, a[1]);
      a[2] = dot2x4(vw[2][c], hvc, a[2]);
      a[3] = dot2x4(vw[3][c], hvc, a[3]);
      a[4] = dot2x4(vw[4][c], hvc, a[4]);
      a[5] = dot2x4(vA, hvc, a[5]);
      a[6] = dot2x4(vB, hvc, a[6]);
      a[7] = dot2x4(vC, hvc, a[7]);
    }
    float b4[4];
    {
      const bool s0 = (W & 1);
      #pragma unroll
      for (int i = 0; i < 4; i++) {
        float keep = s0 ? a[2*i+1] : a[2*i];
        float send = s0 ? a[2*i]   : a[2*i+1];
        b4[i] = keep + dpp_xorf<0xB1>(send);
      }
    }
    float c2[2];
    {
      const bool s1 = (W >> 1) & 1;
      #pragma unroll
      for (int i = 0; i < 2; i++) {
        float keep = s1 ? b4[2*i+1] : b4[2*i];
        float send = s1 ? b4[2*i]   : b4[2*i+1];
        c2[i] = keep + dpp_xorf<0x4E>(send);
      }
    }
    float s;
    {
      const bool s2 = (W >> 2) & 1;
      float keep = s2 ? c2[1] : c2[0];
      float send = s2 ? c2[0] : c2[1];
      s = keep + __shfl_xor(send, 4);
    }
    s += __shfl_xor(s, 8);
    s += __shfl_xor(s, 16);
    if (W < 8) {
      int row = 8*R8 + W;
      int idx = ((row & 63) << 1) | (row >> 6);
      ((uint16_t*)svh32)[idx] = f16b(s);
    }
    lds_barrier();

    float p0 = 0.f, p1 = 0.f;
    { // quarter 0: uint4 0..3
      uint4 sv0 = svh4[0], sv1 = svh4[1], sv2 = svh4[2], sv3 = svh4[3];
      p0 = dot2x4(uq0[0], sv0, p0); p1 = dot2x4(uq1[0], sv0, p1);
      p0 = dot2x4(uq0[1], sv1, p0); p1 = dot2x4(uq1[1], sv1, p1);
      p0 = dot2x4(uq0[2], sv2, p0); p1 = dot2x4(uq1[2], sv2, p1);
      p0 = dot2x4(uq0[3], sv3, p0); p1 = dot2x4(uq1[3], sv3, p1);
    }
    { // quarter 1: uint4 4..7
      uint4 sv0 = svh4[4], sv1 = svh4[5], sv2 = svh4[6], sv3 = svh4[7];
      p0 = dot2x4(uq0[4], sv0, p0); p1 = dot2x4(uq1[4], sv0, p1);
      p0 = dot2x4(uq0[5], sv1, p0); p1 = dot2x4(uq1[5], sv1, p1);
      p0 = dot2x4(uq0[6], sv2, p0); p1 = dot2x4(uq1[6], sv2, p1);
      p0 = dot2x4(uq0[7], sv3, p0); p1 = dot2x4(uq1[7], sv3, p1);
    }
    { // quarter 2: uint4 8..11
      uint4 sv0 = svh4[8], sv1 = svh4[9], sv2 = svh4[10], sv3 = svh4[11];
      p0 = dot2x4(uq0[8],  sv0, p0); p1 = dot2x4(uq1[8],  sv0, p1);
      p0 = dot2x4(uq0[9],  sv1, p0); p1 = dot2x4(uq1[9],  sv1, p1);
      p0 = dot2x4(uq0[10], sv2, p0); p1 = dot2x4(uq1[10], sv2, p1);
      p0 = dot2x4(uq0[11], sv3, p0); p1 = dot2x4(uq1[11], sv3, p1);
    }
    { // quarter 3: uint4 12 streamed + words 52..63 from ulds
      uint4 sv0 = svh4[12], sv1 = svh4[13], sv2 = svh4[14], sv3 = svh4[15];
      uint4 u0b = ulds[0*512 + l], u0c = ulds[1*512 + l], u0d = ulds[2*512 + l];
      uint4 u1b = ulds[3*512 + l], u1c = ulds[4*512 + l], u1d = ulds[5*512 + l];
      p0 = dot2x4(uq0[12], sv0, p0); p1 = dot2x4(uq1[12], sv0, p1);
      p0 = dot2x4(u0b, sv1, p0); p1 = dot2x4(u1b, sv1, p1);
      p0 = dot2x4(u0c, sv2, p0); p1 = dot2x4(u1c, sv2, p1);
      p0 = dot2x4(u0d, sv3, p0); p1 = dot2x4(u1d, sv3, p1);
    }

    float hv0 = fast_tanh(p0 + cc.x);
    float hv1 = fast_tanh(p1 + cc.y);
    *cp2 = make_float2(hv0, hv1);
    ((uint32_t*)hbuf)[20*(l>>4) + (l&15)] = pack2(hv0, hv1);
    *op2 = make_float2(hv0 * fast_silu(zz.x), hv1 * fast_silu(zz.y));
    lds_barrier();

    cp2 += BD/2; zp2 += BD/2; op2 += BD/2;
  }
}

extern "C" void kernel_launch(void* const* d_in, const int* in_sizes, int n_in,
                              void* d_out, int out_size, void* d_ws, size_t ws_size,
                              hipStream_t stream) {
  const float* x  = (const float*)d_in[0];
  const float* z  = (const float*)d_in[1];
  const float* h0 = (const float*)d_in[2];
  const float* Uh = (const float*)d_in[3];
  const float* Vh = (const float*)d_in[4];
  const float* sh = (const float*)d_in[5];
  const float* Ux = (const float*)d_in[6];
  const float* Vx = (const float*)d_in[7];
  const float* sx = (const float*)d_in[8];
  const float* bb = (const float*)d_in[9];
  float* outb = (float*)d_out;
  uint32_t* ws32 = (uint32_t*)d_ws;   // needs 1 MiB

  prep_kernel<<<512, 256, 0, stream>>>(Uh, Vh, sh, Ux, Vx, sx, h0, ws32, outb + TBD);
  inp_kernel<<<T_STEPS, 512, 0, stream>>>(x, ws32, bb, outb + TBD);
  rec_kernel<<<BATCH, 512, 0, stream>>>(ws32, z, outb);
}

// Round 18
// 2121.557 us; speedup vs baseline: 1.2972x; 1.0235x over previous
//
#include <hip/hip_runtime.h>
#include <cstdint>

#define T_STEPS 1024
#define BATCH   32
#define DIM     1024
#define RANK    128
#define BD      (BATCH*DIM)            // 32768
#define TBD     ((size_t)T_STEPS*BD)   // 33554432

typedef _Float16 half2v __attribute__((ext_vector_type(2)));

__device__ __forceinline__ float dot2f(uint32_t a, uint32_t b, float acc) {
#if __has_builtin(__builtin_amdgcn_fdot2)
  return __builtin_amdgcn_fdot2(__builtin_bit_cast(half2v, a),
                                __builtin_bit_cast(half2v, b), acc, false);
#else
  half2v xx = __builtin_bit_cast(half2v, a);
  half2v yy = __builtin_bit_cast(half2v, b);
  return acc + (float)xx[0]*(float)yy[0] + (float)xx[1]*(float)yy[1];
#endif
}

__device__ __forceinline__ float dot2x4(uint4 w, uint4 h, float acc) {
  acc = dot2f(w.x, h.x, acc); acc = dot2f(w.y, h.y, acc);
  acc = dot2f(w.z, h.z, acc); acc = dot2f(w.w, h.w, acc);
  return acc;
}

__device__ __forceinline__ uint16_t f16b(float x) {
  _Float16 h = (_Float16)x;
  return __builtin_bit_cast(unsigned short, h);
}
__device__ __forceinline__ uint32_t pack2(float a, float b) {
  return (uint32_t)f16b(a) | ((uint32_t)f16b(b) << 16);
}
__device__ __forceinline__ float fast_tanh(float x) {
  float e = __expf(2.0f*x);
  return 1.0f - 2.0f/(e + 1.0f);
}
__device__ __forceinline__ float fast_silu(float zz) {
  return zz / (1.0f + __expf(-zz));
}

__device__ __forceinline__ void pin4(uint4 &v) {
  asm volatile("" : "+v"(v.x), "+v"(v.y), "+v"(v.z), "+v"(v.w));
}

template<int CTRL>
__device__ __forceinline__ float dpp_xorf(float v) {
  int t = __builtin_amdgcn_mov_dpp(__builtin_bit_cast(int, v), CTRL, 0xf, 0xf, true);
  return __builtin_bit_cast(float, t);
}

// barrier that does NOT drain vmcnt (only LDS ordering needed between phases)
__device__ __forceinline__ void lds_barrier() {
  asm volatile("s_waitcnt lgkmcnt(0)" ::: "memory");
  __builtin_amdgcn_s_barrier();
  __builtin_amdgcn_sched_barrier(0);
}

// ---------------------------------------------------------------------------
// K0: pack weights (s folded into U), h0 -> h-slot 0.
// ws layout (uint32 words):
//   [0]      vhw  [128][512]   V_h f16 pairs
//   [65536]  uqs  [26][512][4] U'_h stream layout (words 0..51, coalesced)
//   [118784] ures [1024][12]   U'_h words 52..63
//   [131072] vxw  [128][512]   V_x (row-major pairs)
//   [196608] uxc2 [2][16][128][4][4] U'_x for GEMM2 retile: uint4 RP of row d
//            at 196608 + (d>>9)*32768 + RP*2048 + ((d>>2)&127)*16 + (d&3)*4
//            -> per-instr lane pattern (fixed k,RP,dd): contiguous 1KB.
// ---------------------------------------------------------------------------
__global__ void prep_kernel(const float* __restrict__ Uh, const float* __restrict__ Vh,
                            const float* __restrict__ sh, const float* __restrict__ Ux,
                            const float* __restrict__ Vx, const float* __restrict__ sx,
                            const float* __restrict__ h0, uint32_t* __restrict__ ws32,
                            float* __restrict__ hout) {
  int i = blockIdx.x*blockDim.x + threadIdx.x;
  int n = gridDim.x*blockDim.x;
  for (int p = i; p < 65536; p += n) {
    int r = p >> 9, dp = p & 511;
    ws32[p] = pack2(Vh[r*1024 + 2*dp], Vh[r*1024 + 2*dp + 1]);
  }
  for (int p = i; p < 65536; p += n) {
    int d = p >> 6, k = p & 63;
    uint32_t w = pack2(Uh[d*128 + k]      * sh[k],
                       Uh[d*128 + 64 + k] * sh[64 + k]);
    if (k < 52) {
      int J = (k >> 2) + 13*(d & 1);
      ws32[65536 + J*2048 + (d >> 1)*4 + (k & 3)] = w;
    } else {
      ws32[118784 + d*12 + (k - 52)] = w;
    }
  }
  for (int p = i; p < 65536; p += n) {
    int r = p >> 9, dp = p & 511;
    ws32[131072 + p] = pack2(Vx[r*1024 + 2*dp], Vx[r*1024 + 2*dp + 1]);
  }
  for (int p = i; p < 65536; p += n) {
    int d = p >> 6, kw = p & 63;      // word kw = rank pair (2kw, 2kw+1)
    uint32_t w = pack2(Ux[d*128 + 2*kw]   * sx[2*kw],
                       Ux[d*128 + 2*kw+1] * sx[2*kw+1]);
    int RP = kw >> 2, c = kw & 3;
    ws32[196608 + (d >> 9)*32768 + RP*2048 + ((d >> 2) & 127)*16 + (d & 3)*4 + c] = w;
  }
  for (int p = i; p < BD; p += n) hout[p] = h0[p];
}

// ---------------------------------------------------------------------------
// K1: input branch v4. One WG (512 thr) per timestep t.
// GEMM2 RETILED: thread = (bg=l&3 -> b = bg+4j, j<8; dg=l>>2 -> d =
// dd*512 + 4dg + k, k<4). Per RP: 8 sv DS reads + 4 coalesced w reads;
// GEMM2 DS 1024 -> 256 per lane (the R17 diagnosis: inp was DS-instr-bound
// on 1024 uniform svx reads/lane). svx stride 68 words -> the 4 concurrent
// b-addresses (bg=0..3) start at banks {4bg}: conflict-free.
// ---------------------------------------------------------------------------
__global__ __attribute__((amdgpu_flat_work_group_size(512, 512),
                          amdgpu_waves_per_eu(2, 4)))
void inp_kernel(
    const float* __restrict__ x, const uint32_t* __restrict__ ws32,
    const float* __restrict__ bias, float* __restrict__ hout) {
  const int t = blockIdx.x;
  const int l = threadIdx.x;  // 0..511
  __shared__ __attribute__((aligned(16))) uint32_t xs[32*516];   // 66 KB
  __shared__ __attribute__((aligned(16))) uint32_t svx[32*68];   // 8.7 KB

  // stage x_t -> LDS f16 pairs (staggered rows, stride 516)
  const float4* xg = (const float4*)(x + (size_t)t*BD);
  #pragma unroll
  for (int k = 0; k < 16; k++) {
    int i = l + 512*k;
    float4 v = xg[i];
    int bb = i >> 8;
    int d4 = i & 255;
    xs[bb*516 + d4*2]     = pack2(v.x, v.y);
    xs[bb*516 + d4*2 + 1] = pack2(v.z, v.w);
  }
  __syncthreads();

  // ---- GEMM1: sv[b][r] = sum_d Vx[r][d] x[b][d], thread = 4r x 2b ----
  const int rq = l >> 4;      // rows 4rq..4rq+3
  const int bq = l & 15;      // b rows bq, bq+16
  const uint4* xr0 = (const uint4*)(xs + bq*516);
  const uint4* xr1 = (const uint4*)(xs + (bq+16)*516);
  const uint4* wr0 = (const uint4*)(ws32 + 131072 + (4*rq    )*512);
  const uint4* wr1 = (const uint4*)(ws32 + 131072 + (4*rq + 1)*512);
  const uint4* wr2 = (const uint4*)(ws32 + 131072 + (4*rq + 2)*512);
  const uint4* wr3 = (const uint4*)(ws32 + 131072 + (4*rq + 3)*512);
  float a00=0.f,a01=0.f,a10=0.f,a11=0.f,a20=0.f,a21=0.f,a30=0.f,a31=0.f;
  #pragma unroll 2
  for (int J = 0; J < 128; J++) {
    uint4 x0 = xr0[J];
    uint4 x1 = xr1[J];
    uint4 w0 = wr0[J];
    uint4 w1 = wr1[J];
    uint4 w2 = wr2[J];
    uint4 w3 = wr3[J];
    a00 = dot2x4(w0, x0, a00); a01 = dot2x4(w0, x1, a01);
    a10 = dot2x4(w1, x0, a10); a11 = dot2x4(w1, x1, a11);
    a20 = dot2x4(w2, x0, a20); a21 = dot2x4(w2, x1, a21);
    a30 = dot2x4(w3, x0, a30); a31 = dot2x4(w3, x1, a31);
  }
  // svx row b (stride 68 words): word k = f16 pair (r=2k, 2k+1)
  ((uint2*)svx)[bq*34 + rq]      = make_uint2(pack2(a00, a10), pack2(a20, a30));
  ((uint2*)svx)[(bq+16)*34 + rq] = make_uint2(pack2(a01, a11), pack2(a21, a31));
  __syncthreads();

  // ---- GEMM2 (retiled): c[b][d] = sum_r Ux'[d][r] sv[b][r] + bias[d] ----
  const int bg = l & 3;       // b = bg + 4j, j = 0..7
  const int dg = l >> 2;      // d = dd*512 + 4*dg + k, k = 0..3
  const uint4* sv4 = (const uint4*)svx;   // row b at uint4 b*17
  float* cbase = hout + (size_t)(t+1)*BD;
  #pragma unroll 1
  for (int dd = 0; dd < 2; dd++) {
    const uint4* uw = (const uint4*)(ws32 + 196608 + dd*32768);  // + RP*512 + dg*4 + k
    float acc[4][8];
    #pragma unroll
    for (int k = 0; k < 4; k++)
      #pragma unroll
      for (int j = 0; j < 8; j++) acc[k][j] = 0.f;
    #pragma unroll
    for (int RP = 0; RP < 16; RP++) {
      uint4 w0 = uw[RP*512 + dg*4 + 0];
      uint4 w1 = uw[RP*512 + dg*4 + 1];
      uint4 w2 = uw[RP*512 + dg*4 + 2];
      uint4 w3 = uw[RP*512 + dg*4 + 3];
      #pragma unroll
      for (int j = 0; j < 8; j++) {
        uint4 sv = sv4[(bg + 4*j)*17 + RP];
        acc[0][j] = dot2x4(w0, sv, acc[0][j]);
        acc[1][j] = dot2x4(w1, sv, acc[1][j]);
        acc[2][j] = dot2x4(w2, sv, acc[2][j]);
        acc[3][j] = dot2x4(w3, sv, acc[3][j]);
      }
    }
    #pragma unroll
    for (int k = 0; k < 4; k++) {
      int d = dd*512 + 4*dg + k;
      float bv = bias[d];
      #pragma unroll
      for (int j = 0; j < 8; j++) {
        int b = bg + 4*j;
        cbase[(size_t)b*DIM + d] = acc[k][j] + bv;
      }
    }
  }
}

// ---------------------------------------------------------------------------
// K2: recurrence (R16/R17 verbatim, best: 1766us). One WG (512 thr,
// 2 waves/SIMD) per batch. regs 80 w V (pinned); LDS 147 KB; stream 208 KB/
// step U words 0..51 (coalesced, remat'd); svh direct uniform b128 reads.
// ---------------------------------------------------------------------------
__global__ __attribute__((amdgpu_flat_work_group_size(512, 512),
                          amdgpu_waves_per_eu(2, 2)))
void rec_kernel(
    const uint32_t* __restrict__ ws32, const float* __restrict__ z,
    float* __restrict__ outb) {
  const int b  = blockIdx.x;
  const int l  = threadIdx.x;  // 0..511
  const int W  = l & 31;
  const int R8 = l >> 5;       // 0..15
  float* hout = outb + TBD;
  const uint4* vhw4  = (const uint4*)ws32;
  const uint4* uqs4  = (const uint4*)(ws32 + 65536);
  const uint4* ures4 = (const uint4*)(ws32 + 118784);

  __shared__ __attribute__((aligned(16))) uint4    vlds[6144];   // 96 KB
  __shared__ __attribute__((aligned(16))) uint4    ulds[3072];   // 48 KB
  __shared__ __attribute__((aligned(16))) uint4    hbuf[32*5];   // 2.5 KB staggered
  __shared__ __attribute__((aligned(16))) uint32_t svh32[64];    // 256 B

  uint4 vw[5][4];
  #pragma unroll
  for (int r = 0; r < 5; r++) {
    #pragma unroll
    for (int c = 0; c < 4; c++) vw[r][c] = vhw4[(8*R8 + r)*128 + W*4 + c];
  }
  #pragma unroll
  for (int r = 0; r < 5; r++) {
    #pragma unroll
    for (int c = 0; c < 4; c++) pin4(vw[r][c]);
  }
  #pragma unroll
  for (int rr = 0; rr < 3; rr++) {
    #pragma unroll
    for (int c = 0; c < 4; c++)
      vlds[R8*384 + rr*128 + c*32 + W] = vhw4[(8*R8 + 5 + rr)*128 + W*4 + c];
  }
  #pragma unroll
  for (int j = 0; j < 3; j++) {
    ulds[j*512 + l]     = ures4[(2*l)*3 + j];
    ulds[(3+j)*512 + l] = ures4[(2*l+1)*3 + j];
  }
  uint4 uq0[13], uq1[13];
  #pragma unroll
  for (int J = 0; J < 13; J++) {
    uq0[J] = uqs4[J*512 + l];
    uq1[J] = uqs4[(13+J)*512 + l];
  }
  {
    const float2 v = ((const float2*)(hout + (size_t)b*DIM))[l];
    ((uint32_t*)hbuf)[20*(l>>4) + (l&15)] = pack2(v.x, v.y);
  }
  __syncthreads();

  const float2* zp2 = (const float2*)(z + (size_t)b*DIM) + l;
  float2*       cp2 = (float2*)(hout + BD + (size_t)b*DIM) + l;
  float2*       op2 = (float2*)(outb + (size_t)b*DIM) + l;
  const uint4*  hb4  = hbuf + W*5;
  const uint4*  svh4 = (const uint4*)svh32;
  const int vbase = R8*384;

  #pragma unroll 1
  for (int t = 0; t < T_STEPS; t++) {
    float2 cc = *cp2;
    float2 zz = *zp2;

    float a[8] = {0.f,0.f,0.f,0.f,0.f,0.f,0.f,0.f};
    #pragma unroll
    for (int c = 0; c < 4; c++) {
      uint4 hvc = hb4[c];
      uint4 vA = vlds[vbase + c*32 + W];
      uint4 vB = vlds[vbase + 128 + c*32 + W];
      uint4 vC = vlds[vbase + 256 + c*32 + W];
      a[0] = dot2x4(vw[0][c], hvc, a[0]);
      a[1] = dot2x4(vw[1][c], hvc, a[1]);
      a[2] = dot2x4(vw[2][c], hvc, a[2]);
      a[3] = dot2x4(vw[3][c], hvc, a[3]);
      a[4] = dot2x4(vw[4][c], hvc, a[4]);
      a[5] = dot2x4(vA, hvc, a[5]);
      a[6] = dot2x4(vB, hvc, a[6]);
      a[7] = dot2x4(vC, hvc, a[7]);
    }
    float b4[4];
    {
      const bool s0 = (W & 1);
      #pragma unroll
      for (int i = 0; i < 4; i++) {
        float keep = s0 ? a[2*i+1] : a[2*i];
        float send = s0 ? a[2*i]   : a[2*i+1];
        b4[i] = keep + dpp_xorf<0xB1>(send);
      }
    }
    float c2[2];
    {
      const bool s1 = (W >> 1) & 1;
      #pragma unroll
      for (int i = 0; i < 2; i++) {
        float keep = s1 ? b4[2*i+1] : b4[2*i];
        float send = s1 ? b4[2*i]   : b4[2*i+1];
        c2[i] = keep + dpp_xorf<0x4E>(send);
      }
    }
    float s;
    {
      const bool s2 = (W >> 2) & 1;
      float keep = s2 ? c2[1] : c2[0];
      float send = s2 ? c2[0] : c2[1];
      s = keep + __shfl_xor(send, 4);
    }
    s += __shfl_xor(s, 8);
    s += __shfl_xor(s, 16);
    if (W < 8) {
      int row = 8*R8 + W;
      int idx = ((row & 63) << 1) | (row >> 6);
      ((uint16_t*)svh32)[idx] = f16b(s);
    }
    lds_barrier();

    float p0 = 0.f, p1 = 0.f;
    { // quarter 0: uint4 0..3
      uint4 sv0 = svh4[0], sv1 = svh4[1], sv2 = svh4[2], sv3 = svh4[3];
      p0 = dot2x4(uq0[0], sv0, p0); p1 = dot2x4(uq1[0], sv0, p1);
      p0 = dot2x4(uq0[1], sv1, p0); p1 = dot2x4(uq1[1], sv1, p1);
      p0 = dot2x4(uq0[2], sv2, p0); p1 = dot2x4(uq1[2], sv2, p1);
      p0 = dot2x4(uq0[3], sv3, p0); p1 = dot2x4(uq1[3], sv3, p1);
    }
    { // quarter 1: uint4 4..7
      uint4 sv0 = svh4[4], sv1 = svh4[5], sv2 = svh4[6], sv3 = svh4[7];
      p0 = dot2x4(uq0[4], sv0, p0); p1 = dot2x4(uq1[4], sv0, p1);
      p0 = dot2x4(uq0[5], sv1, p0); p1 = dot2x4(uq1[5], sv1, p1);
      p0 = dot2x4(uq0[6], sv2, p0); p1 = dot2x4(uq1[6], sv2, p1);
      p0 = dot2x4(uq0[7], sv3, p0); p1 = dot2x4(uq1[7], sv3, p1);
    }
    { // quarter 2: uint4 8..11
      uint4 sv0 = svh4[8], sv1 = svh4[9], sv2 = svh4[10], sv3 = svh4[11];
      p0 = dot2x4(uq0[8],  sv0, p0); p1 = dot2x4(uq1[8],  sv0, p1);
      p0 = dot2x4(uq0[9],  sv1, p0); p1 = dot2x4(uq1[9],  sv1, p1);
      p0 = dot2x4(uq0[10], sv2, p0); p1 = dot2x4(uq1[10], sv2, p1);
      p0 = dot2x4(uq0[11], sv3, p0); p1 = dot2x4(uq1[11], sv3, p1);
    }
    { // quarter 3: uint4 12 streamed + words 52..63 from ulds
      uint4 sv0 = svh4[12], sv1 = svh4[13], sv2 = svh4[14], sv3 = svh4[15];
      uint4 u0b = ulds[0*512 + l], u0c = ulds[1*512 + l], u0d = ulds[2*512 + l];
      uint4 u1b = ulds[3*512 + l], u1c = ulds[4*512 + l], u1d = ulds[5*512 + l];
      p0 = dot2x4(uq0[12], sv0, p0); p1 = dot2x4(uq1[12], sv0, p1);
      p0 = dot2x4(u0b, sv1, p0); p1 = dot2x4(u1b, sv1, p1);
      p0 = dot2x4(u0c, sv2, p0); p1 = dot2x4(u1c, sv2, p1);
      p0 = dot2x4(u0d, sv3, p0); p1 = dot2x4(u1d, sv3, p1);
    }

    float hv0 = fast_tanh(p0 + cc.x);
    float hv1 = fast_tanh(p1 + cc.y);
    *cp2 = make_float2(hv0, hv1);
    ((uint32_t*)hbuf)[20*(l>>4) + (l&15)] = pack2(hv0, hv1);
    *op2 = make_float2(hv0 * fast_silu(zz.x), hv1 * fast_silu(zz.y));
    lds_barrier();

    cp2 += BD/2; zp2 += BD/2; op2 += BD/2;
  }
}

extern "C" void kernel_launch(void* const* d_in, const int* in_sizes, int n_in,
                              void* d_out, int out_size, void* d_ws, size_t ws_size,
                              hipStream_t stream) {
  const float* x  = (const float*)d_in[0];
  const float* z  = (const float*)d_in[1];
  const float* h0 = (const float*)d_in[2];
  const float* Uh = (const float*)d_in[3];
  const float* Vh = (const float*)d_in[4];
  const float* sh = (const float*)d_in[5];
  const float* Ux = (const float*)d_in[6];
  const float* Vx = (const float*)d_in[7];
  const float* sx = (const float*)d_in[8];
  const float* bb = (const float*)d_in[9];
  float* outb = (float*)d_out;
  uint32_t* ws32 = (uint32_t*)d_ws;   // needs 1 MiB

  prep_kernel<<<512, 256, 0, stream>>>(Uh, Vh, sh, Ux, Vx, sx, h0, ws32, outb + TBD);
  inp_kernel<<<T_STEPS, 512, 0, stream>>>(x, ws32, bb, outb + TBD);
  rec_kernel<<<BATCH, 512, 0, stream>>>(ws32, z, outb);
}

// Round 19
// 1990.709 us; speedup vs baseline: 1.3824x; 1.0657x over previous
//
#include <hip/hip_runtime.h>
#include <cstdint>

#define T_STEPS 1024
#define BATCH   32
#define DIM     1024
#define RANK    128
#define BD      (BATCH*DIM)            // 32768
#define TBD     ((size_t)T_STEPS*BD)   // 33554432

typedef _Float16 half2v __attribute__((ext_vector_type(2)));

__device__ __forceinline__ float dot2f(uint32_t a, uint32_t b, float acc) {
#if __has_builtin(__builtin_amdgcn_fdot2)
  return __builtin_amdgcn_fdot2(__builtin_bit_cast(half2v, a),
                                __builtin_bit_cast(half2v, b), acc, false);
#else
  half2v xx = __builtin_bit_cast(half2v, a);
  half2v yy = __builtin_bit_cast(half2v, b);
  return acc + (float)xx[0]*(float)yy[0] + (float)xx[1]*(float)yy[1];
#endif
}

__device__ __forceinline__ float dot2x4(uint4 w, uint4 h, float acc) {
  acc = dot2f(w.x, h.x, acc); acc = dot2f(w.y, h.y, acc);
  acc = dot2f(w.z, h.z, acc); acc = dot2f(w.w, h.w, acc);
  return acc;
}

__device__ __forceinline__ uint16_t f16b(float x) {
  _Float16 h = (_Float16)x;
  return __builtin_bit_cast(unsigned short, h);
}
__device__ __forceinline__ uint32_t pack2(float a, float b) {
  return (uint32_t)f16b(a) | ((uint32_t)f16b(b) << 16);
}
__device__ __forceinline__ float fast_tanh(float x) {
  float e = __expf(2.0f*x);
  return 1.0f - 2.0f/(e + 1.0f);
}
__device__ __forceinline__ float fast_silu(float zz) {
  return zz / (1.0f + __expf(-zz));
}

__device__ __forceinline__ void pin4(uint4 &v) {
  asm volatile("" : "+v"(v.x), "+v"(v.y), "+v"(v.z), "+v"(v.w));
}

template<int CTRL>
__device__ __forceinline__ float dpp_xorf(float v) {
  int t = __builtin_amdgcn_mov_dpp(__builtin_bit_cast(int, v), CTRL, 0xf, 0xf, true);
  return __builtin_bit_cast(float, t);
}

// barrier that does NOT drain vmcnt (only LDS ordering needed between phases)
__device__ __forceinline__ void lds_barrier() {
  asm volatile("s_waitcnt lgkmcnt(0)" ::: "memory");
  __builtin_amdgcn_s_barrier();
  __builtin_amdgcn_sched_barrier(0);
}

// ---------------------------------------------------------------------------
// K0: pack weights (s folded into U), h0 -> h-slot 0.
// ws layout (uint32 words):
//   [0]      vhw  [128][512]   V_h f16 pairs
//   [65536]  uqs  [26][512][4] U'_h stream layout (words 0..51, coalesced)
//   [118784] ures [1024][12]   U'_h words 52..63
//   [131072] vxw  [128][512]   V_x (row-major pairs)
//   [196608] uxc2 [2][16][128][4][4] U'_x: uint4 RP of row d at
//            196608 + (d>>9)*32768 + RP*2048 + ((d>>2)&127)*16 + (d&3)*4
// ---------------------------------------------------------------------------
__global__ void prep_kernel(const float* __restrict__ Uh, const float* __restrict__ Vh,
                            const float* __restrict__ sh, const float* __restrict__ Ux,
                            const float* __restrict__ Vx, const float* __restrict__ sx,
                            const float* __restrict__ h0, uint32_t* __restrict__ ws32,
                            float* __restrict__ hout) {
  int i = blockIdx.x*blockDim.x + threadIdx.x;
  int n = gridDim.x*blockDim.x;
  for (int p = i; p < 65536; p += n) {
    int r = p >> 9, dp = p & 511;
    ws32[p] = pack2(Vh[r*1024 + 2*dp], Vh[r*1024 + 2*dp + 1]);
  }
  for (int p = i; p < 65536; p += n) {
    int d = p >> 6, k = p & 63;
    uint32_t w = pack2(Uh[d*128 + k]      * sh[k],
                       Uh[d*128 + 64 + k] * sh[64 + k]);
    if (k < 52) {
      int J = (k >> 2) + 13*(d & 1);
      ws32[65536 + J*2048 + (d >> 1)*4 + (k & 3)] = w;
    } else {
      ws32[118784 + d*12 + (k - 52)] = w;
    }
  }
  for (int p = i; p < 65536; p += n) {
    int r = p >> 9, dp = p & 511;
    ws32[131072 + p] = pack2(Vx[r*1024 + 2*dp], Vx[r*1024 + 2*dp + 1]);
  }
  for (int p = i; p < 65536; p += n) {
    int d = p >> 6, kw = p & 63;      // word kw = rank pair (2kw, 2kw+1)
    uint32_t w = pack2(Ux[d*128 + 2*kw]   * sx[2*kw],
                       Ux[d*128 + 2*kw+1] * sx[2*kw+1]);
    int RP = kw >> 2, c = kw & 3;
    ws32[196608 + (d >> 9)*32768 + RP*2048 + ((d >> 2) & 127)*16 + (d & 3)*4 + c] = w;
  }
  for (int p = i; p < BD; p += n) hout[p] = h0[p];
}

// ---------------------------------------------------------------------------
// K1: input branch v5. One WG (512 thr) per timestep t.
// vs v4: (a) xs staging uses b64 writes (32 -> 16 DS writes/lane);
// (b) GEMM2 fold-dd: RP-outer, 8 sv reads shared across BOTH dd halves ->
// sv DS 256 -> 128/lane. acc[2][4][8]=64 regs; accumulation order per
// output unchanged (bit-identical c).
// ---------------------------------------------------------------------------
__global__ __attribute__((amdgpu_flat_work_group_size(512, 512),
                          amdgpu_waves_per_eu(2, 4)))
void inp_kernel(
    const float* __restrict__ x, const uint32_t* __restrict__ ws32,
    const float* __restrict__ bias, float* __restrict__ hout) {
  const int t = blockIdx.x;
  const int l = threadIdx.x;  // 0..511
  __shared__ __attribute__((aligned(16))) uint32_t xs[32*516];   // 66 KB
  __shared__ __attribute__((aligned(16))) uint32_t svx[32*68];   // 8.7 KB

  // stage x_t -> LDS f16 pairs (staggered rows, stride 516), b64 writes
  const float4* xg = (const float4*)(x + (size_t)t*BD);
  #pragma unroll
  for (int k = 0; k < 16; k++) {
    int i = l + 512*k;
    float4 v = xg[i];
    int bb = i >> 8;
    int d4 = i & 255;
    ((uint2*)(xs + bb*516))[d4] = make_uint2(pack2(v.x, v.y), pack2(v.z, v.w));
  }
  __syncthreads();

  // ---- GEMM1: sv[b][r] = sum_d Vx[r][d] x[b][d], thread = 4r x 2b ----
  const int rq = l >> 4;      // rows 4rq..4rq+3
  const int bq = l & 15;      // b rows bq, bq+16
  const uint4* xr0 = (const uint4*)(xs + bq*516);
  const uint4* xr1 = (const uint4*)(xs + (bq+16)*516);
  const uint4* wr0 = (const uint4*)(ws32 + 131072 + (4*rq    )*512);
  const uint4* wr1 = (const uint4*)(ws32 + 131072 + (4*rq + 1)*512);
  const uint4* wr2 = (const uint4*)(ws32 + 131072 + (4*rq + 2)*512);
  const uint4* wr3 = (const uint4*)(ws32 + 131072 + (4*rq + 3)*512);
  float a00=0.f,a01=0.f,a10=0.f,a11=0.f,a20=0.f,a21=0.f,a30=0.f,a31=0.f;
  #pragma unroll 2
  for (int J = 0; J < 128; J++) {
    uint4 x0 = xr0[J];
    uint4 x1 = xr1[J];
    uint4 w0 = wr0[J];
    uint4 w1 = wr1[J];
    uint4 w2 = wr2[J];
    uint4 w3 = wr3[J];
    a00 = dot2x4(w0, x0, a00); a01 = dot2x4(w0, x1, a01);
    a10 = dot2x4(w1, x0, a10); a11 = dot2x4(w1, x1, a11);
    a20 = dot2x4(w2, x0, a20); a21 = dot2x4(w2, x1, a21);
    a30 = dot2x4(w3, x0, a30); a31 = dot2x4(w3, x1, a31);
  }
  // svx row b (stride 68 words): word k = f16 pair (r=2k, 2k+1)
  ((uint2*)svx)[bq*34 + rq]      = make_uint2(pack2(a00, a10), pack2(a20, a30));
  ((uint2*)svx)[(bq+16)*34 + rq] = make_uint2(pack2(a01, a11), pack2(a21, a31));
  __syncthreads();

  // ---- GEMM2 (fold-dd): c[b][d] = sum_r Ux'[d][r] sv[b][r] + bias[d] ----
  const int bg = l & 3;       // b = bg + 4j, j = 0..7
  const int dg = l >> 2;      // d = dd*512 + 4*dg + k, k = 0..3
  const uint4* sv4 = (const uint4*)svx;   // row b at uint4 b*17
  const uint4* uw  = (const uint4*)(ws32 + 196608);  // + dd*8192 + RP*512 + dg*4 + k
  float acc[2][4][8];
  #pragma unroll
  for (int dd = 0; dd < 2; dd++)
    #pragma unroll
    for (int k = 0; k < 4; k++)
      #pragma unroll
      for (int j = 0; j < 8; j++) acc[dd][k][j] = 0.f;
  #pragma unroll
  for (int RP = 0; RP < 16; RP++) {
    uint4 sv[8];
    #pragma unroll
    for (int j = 0; j < 8; j++) sv[j] = sv4[(bg + 4*j)*17 + RP];
    #pragma unroll
    for (int dd = 0; dd < 2; dd++) {
      uint4 w0 = uw[dd*8192 + RP*512 + dg*4 + 0];
      uint4 w1 = uw[dd*8192 + RP*512 + dg*4 + 1];
      uint4 w2 = uw[dd*8192 + RP*512 + dg*4 + 2];
      uint4 w3 = uw[dd*8192 + RP*512 + dg*4 + 3];
      #pragma unroll
      for (int j = 0; j < 8; j++) {
        acc[dd][0][j] = dot2x4(w0, sv[j], acc[dd][0][j]);
        acc[dd][1][j] = dot2x4(w1, sv[j], acc[dd][1][j]);
        acc[dd][2][j] = dot2x4(w2, sv[j], acc[dd][2][j]);
        acc[dd][3][j] = dot2x4(w3, sv[j], acc[dd][3][j]);
      }
    }
  }
  float* cbase = hout + (size_t)(t+1)*BD;
  #pragma unroll
  for (int dd = 0; dd < 2; dd++) {
    #pragma unroll
    for (int k = 0; k < 4; k++) {
      int d = dd*512 + 4*dg + k;
      float bv = bias[d];
      #pragma unroll
      for (int j = 0; j < 8; j++) {
        int b = bg + 4*j;
        cbase[(size_t)b*DIM + d] = acc[dd][k][j] + bv;
      }
    }
  }
}

// ---------------------------------------------------------------------------
// K2: recurrence (R16-R18 verbatim, 1766-1772us stable). One WG (512 thr,
// 2 waves/SIMD) per batch. regs 80 w V (pinned); LDS 147 KB; stream 208 KB/
// step U words 0..51 (coalesced, remat'd); svh direct uniform b128 reads.
// Measured 50 B/cyc/CU L2-stream (~85-90% of per-CU ceiling) co-bound with
// ~3840 cyc/step DS issue -> structural floor for this decomposition.
// ---------------------------------------------------------------------------
__global__ __attribute__((amdgpu_flat_work_group_size(512, 512),
                          amdgpu_waves_per_eu(2, 2)))
void rec_kernel(
    const uint32_t* __restrict__ ws32, const float* __restrict__ z,
    float* __restrict__ outb) {
  const int b  = blockIdx.x;
  const int l  = threadIdx.x;  // 0..511
  const int W  = l & 31;
  const int R8 = l >> 5;       // 0..15
  float* hout = outb + TBD;
  const uint4* vhw4  = (const uint4*)ws32;
  const uint4* uqs4  = (const uint4*)(ws32 + 65536);
  const uint4* ures4 = (const uint4*)(ws32 + 118784);

  __shared__ __attribute__((aligned(16))) uint4    vlds[6144];   // 96 KB
  __shared__ __attribute__((aligned(16))) uint4    ulds[3072];   // 48 KB
  __shared__ __attribute__((aligned(16))) uint4    hbuf[32*5];   // 2.5 KB staggered
  __shared__ __attribute__((aligned(16))) uint32_t svh32[64];    // 256 B

  uint4 vw[5][4];
  #pragma unroll
  for (int r = 0; r < 5; r++) {
    #pragma unroll
    for (int c = 0; c < 4; c++) vw[r][c] = vhw4[(8*R8 + r)*128 + W*4 + c];
  }
  #pragma unroll
  for (int r = 0; r < 5; r++) {
    #pragma unroll
    for (int c = 0; c < 4; c++) pin4(vw[r][c]);
  }
  #pragma unroll
  for (int rr = 0; rr < 3; rr++) {
    #pragma unroll
    for (int c = 0; c < 4; c++)
      vlds[R8*384 + rr*128 + c*32 + W] = vhw4[(8*R8 + 5 + rr)*128 + W*4 + c];
  }
  #pragma unroll
  for (int j = 0; j < 3; j++) {
    ulds[j*512 + l]     = ures4[(2*l)*3 + j];
    ulds[(3+j)*512 + l] = ures4[(2*l+1)*3 + j];
  }
  uint4 uq0[13], uq1[13];
  #pragma unroll
  for (int J = 0; J < 13; J++) {
    uq0[J] = uqs4[J*512 + l];
    uq1[J] = uqs4[(13+J)*512 + l];
  }
  {
    const float2 v = ((const float2*)(hout + (size_t)b*DIM))[l];
    ((uint32_t*)hbuf)[20*(l>>4) + (l&15)] = pack2(v.x, v.y);
  }
  __syncthreads();

  const float2* zp2 = (const float2*)(z + (size_t)b*DIM) + l;
  float2*       cp2 = (float2*)(hout + BD + (size_t)b*DIM) + l;
  float2*       op2 = (float2*)(outb + (size_t)b*DIM) + l;
  const uint4*  hb4  = hbuf + W*5;
  const uint4*  svh4 = (const uint4*)svh32;
  const int vbase = R8*384;

  #pragma unroll 1
  for (int t = 0; t < T_STEPS; t++) {
    float2 cc = *cp2;
    float2 zz = *zp2;

    float a[8] = {0.f,0.f,0.f,0.f,0.f,0.f,0.f,0.f};
    #pragma unroll
    for (int c = 0; c < 4; c++) {
      uint4 hvc = hb4[c];
      uint4 vA = vlds[vbase + c*32 + W];
      uint4 vB = vlds[vbase + 128 + c*32 + W];
      uint4 vC = vlds[vbase + 256 + c*32 + W];
      a[0] = dot2x4(vw[0][c], hvc, a[0]);
      a[1] = dot2x4(vw[1][c], hvc, a[1]);
      a[2] = dot2x4(vw[2][c], hvc, a[2]);
      a[3] = dot2x4(vw[3][c], hvc, a[3]);
      a[4] = dot2x4(vw[4][c], hvc, a[4]);
      a[5] = dot2x4(vA, hvc, a[5]);
      a[6] = dot2x4(vB, hvc, a[6]);
      a[7] = dot2x4(vC, hvc, a[7]);
    }
    float b4[4];
    {
      const bool s0 = (W & 1);
      #pragma unroll
      for (int i = 0; i < 4; i++) {
        float keep = s0 ? a[2*i+1] : a[2*i];
        float send = s0 ? a[2*i]   : a[2*i+1];
        b4[i] = keep + dpp_xorf<0xB1>(send);
      }
    }
    float c2[2];
    {
      const bool s1 = (W >> 1) & 1;
      #pragma unroll
      for (int i = 0; i < 2; i++) {
        float keep = s1 ? b4[2*i+1] : b4[2*i];
        float send = s1 ? b4[2*i]   : b4[2*i+1];
        c2[i] = keep + dpp_xorf<0x4E>(send);
      }
    }
    float s;
    {
      const bool s2 = (W >> 2) & 1;
      float keep = s2 ? c2[1] : c2[0];
      float send = s2 ? c2[0] : c2[1];
      s = keep + __shfl_xor(send, 4);
    }
    s += __shfl_xor(s, 8);
    s += __shfl_xor(s, 16);
    if (W < 8) {
      int row = 8*R8 + W;
      int idx = ((row & 63) << 1) | (row >> 6);
      ((uint16_t*)svh32)[idx] = f16b(s);
    }
    lds_barrier();

    float p0 = 0.f, p1 = 0.f;
    { // quarter 0: uint4 0..3
      uint4 sv0 = svh4[0], sv1 = svh4[1], sv2 = svh4[2], sv3 = svh4[3];
      p0 = dot2x4(uq0[0], sv0, p0); p1 = dot2x4(uq1[0], sv0, p1);
      p0 = dot2x4(uq0[1], sv1, p0); p1 = dot2x4(uq1[1], sv1, p1);
      p0 = dot2x4(uq0[2], sv2, p0); p1 = dot2x4(uq1[2], sv2, p1);
      p0 = dot2x4(uq0[3], sv3, p0); p1 = dot2x4(uq1[3], sv3, p1);
    }
    { // quarter 1: uint4 4..7
      uint4 sv0 = svh4[4], sv1 = svh4[5], sv2 = svh4[6], sv3 = svh4[7];
      p0 = dot2x4(uq0[4], sv0, p0); p1 = dot2x4(uq1[4], sv0, p1);
      p0 = dot2x4(uq0[5], sv1, p0); p1 = dot2x4(uq1[5], sv1, p1);
      p0 = dot2x4(uq0[6], sv2, p0); p1 = dot2x4(uq1[6], sv2, p1);
      p0 = dot2x4(uq0[7], sv3, p0); p1 = dot2x4(uq1[7], sv3, p1);
    }
    { // quarter 2: uint4 8..11
      uint4 sv0 = svh4[8], sv1 = svh4[9], sv2 = svh4[10], sv3 = svh4[11];
      p0 = dot2x4(uq0[8],  sv0, p0); p1 = dot2x4(uq1[8],  sv0, p1);
      p0 = dot2x4(uq0[9],  sv1, p0); p1 = dot2x4(uq1[9],  sv1, p1);
      p0 = dot2x4(uq0[10], sv2, p0); p1 = dot2x4(uq1[10], sv2, p1);
      p0 = dot2x4(uq0[11], sv3, p0); p1 = dot2x4(uq1[11], sv3, p1);
    }
    { // quarter 3: uint4 12 streamed + words 52..63 from ulds
      uint4 sv0 = svh4[12], sv1 = svh4[13], sv2 = svh4[14], sv3 = svh4[15];
      uint4 u0b = ulds[0*512 + l], u0c = ulds[1*512 + l], u0d = ulds[2*512 + l];
      uint4 u1b = ulds[3*512 + l], u1c = ulds[4*512 + l], u1d = ulds[5*512 + l];
      p0 = dot2x4(uq0[12], sv0, p0); p1 = dot2x4(uq1[12], sv0, p1);
      p0 = dot2x4(u0b, sv1, p0); p1 = dot2x4(u1b, sv1, p1);
      p0 = dot2x4(u0c, sv2, p0); p1 = dot2x4(u1c, sv2, p1);
      p0 = dot2x4(u0d, sv3, p0); p1 = dot2x4(u1d, sv3, p1);
    }

    float hv0 = fast_tanh(p0 + cc.x);
    float hv1 = fast_tanh(p1 + cc.y);
    *cp2 = make_float2(hv0, hv1);
    ((uint32_t*)hbuf)[20*(l>>4) + (l&15)] = pack2(hv0, hv1);
    *op2 = make_float2(hv0 * fast_silu(zz.x), hv1 * fast_silu(zz.y));
    lds_barrier();

    cp2 += BD/2; zp2 += BD/2; op2 += BD/2;
  }
}

extern "C" void kernel_launch(void* const* d_in, const int* in_sizes, int n_in,
                              void* d_out, int out_size, void* d_ws, size_t ws_size,
                              hipStream_t stream) {
  const float* x  = (const float*)d_in[0];
  const float* z  = (const float*)d_in[1];
  const float* h0 = (const float*)d_in[2];
  const float* Uh = (const float*)d_in[3];
  const float* Vh = (const float*)d_in[4];
  const float* sh = (const float*)d_in[5];
  const float* Ux = (const float*)d_in[6];
  const float* Vx = (const float*)d_in[7];
  const float* sx = (const float*)d_in[8];
  const float* bb = (const float*)d_in[9];
  float* outb = (float*)d_out;
  uint32_t* ws32 = (uint32_t*)d_ws;   // needs 1 MiB

  prep_kernel<<<512, 256, 0, stream>>>(Uh, Vh, sh, Ux, Vx, sx, h0, ws32, outb + TBD);
  inp_kernel<<<T_STEPS, 512, 0, stream>>>(x, ws32, bb, outb + TBD);
  rec_kernel<<<BATCH, 512, 0, stream>>>(ws32, z, outb);
}